// Round 9
// baseline (4032.540 us; speedup 1.0000x reference)
//
#include <hip/hip_runtime.h>
#include <hip/hip_bf16.h>
#include <math.h>

#define NN   20000
#define NE   320000
#define TT   24
#define SDIM 16
#define DDIM 8
#define HID  128
#define HEADS 4
#define DPH  32
#define NL   3
#define TC   4          // timesteps batched per GNN chunk (divides TT)

typedef unsigned short u16;
typedef unsigned int   u32;
typedef __attribute__((ext_vector_type(8))) short  short8;
typedef __attribute__((ext_vector_type(4))) float  floatx4;

__device__ __forceinline__ u16 f2bf(float x) {          // round-to-nearest-even
  u32 u = __float_as_uint(x);
  return (u16)((u + 0x7fff + ((u >> 16) & 1)) >> 16);
}
__device__ __forceinline__ float bf2f(u16 b) {
  return __uint_as_float(((u32)b) << 16);
}

// ---------------- CSR build (group edges by dst) ----------------
__global__ void k_count(const int* __restrict__ dst, int* __restrict__ cnt) {
  int e = blockIdx.x * 256 + threadIdx.x;
  if (e < NE) atomicAdd(&cnt[dst[e]], 1);
}

__global__ __launch_bounds__(1024) void k_scan(const int* __restrict__ cnt,
    int* __restrict__ rowptr, int* __restrict__ cursor) {
  __shared__ int sh[1024];
  int tid = threadIdx.x;
  const int CH = 20;                      // 1024*20 >= NN
  int base = tid * CH;
  int local[CH];
  int s = 0;
  #pragma unroll
  for (int i = 0; i < CH; i++) {
    int idx = base + i;
    int v = (idx < NN) ? cnt[idx] : 0;
    local[i] = s;
    s += v;
  }
  sh[tid] = s;
  __syncthreads();
  for (int off = 1; off < 1024; off <<= 1) {
    int tv = (tid >= off) ? sh[tid - off] : 0;
    __syncthreads();
    sh[tid] += tv;
    __syncthreads();
  }
  int pre = (tid > 0) ? sh[tid - 1] : 0;
  #pragma unroll
  for (int i = 0; i < CH; i++) {
    int idx = base + i;
    if (idx < NN) { int e = pre + local[i]; rowptr[idx] = e; cursor[idx] = e; }
  }
  if (tid == 1023) rowptr[NN] = sh[1023];
}

__global__ void k_fill(const int* __restrict__ src, const int* __restrict__ dst,
    int* __restrict__ cursor, int* __restrict__ col) {
  int e = blockIdx.x * 256 + threadIdx.x;
  if (e < NE) {
    int pos = atomicAdd(&cursor[dst[e]], 1);
    col[pos] = src[e];
  }
}

// ---------------- weight prep ----------------
// LSTM weights, GATE-INTERLEAVED: Bt[4c+g][k] = W[g*128+c][k], W = [Wih | Whh]
__global__ void k_prepw_lstm(const float* __restrict__ Wih, const float* __restrict__ Whh,
    u16* __restrict__ Bt) {
  int idx = blockIdx.x * 256 + threadIdx.x;
  if (idx < 512 * 256) {
    int jp = idx >> 8, k = idx & 255;
    int c = jp >> 2, g = jp & 3;
    int j = g * 128 + c;
    float v = (k < 128) ? Wih[(size_t)j * 128 + k] : Whh[(size_t)j * 128 + (k - 128)];
    Bt[idx] = f2bf(v);
  }
}
// combined bias, gate-interleaved: bs[4c+g] = bih[g*128+c] + bhh[g*128+c]; 2 cells
__global__ void k_prepb(const float* __restrict__ bih0, const float* __restrict__ bhh0,
    const float* __restrict__ bih1, const float* __restrict__ bhh1,
    float* __restrict__ bs01) {
  int t = threadIdx.x;               // 512 per block, blockIdx.x = cell
  const float* bih = blockIdx.x ? bih1 : bih0;
  const float* bhh = blockIdx.x ? bhh1 : bhh0;
  int c = t >> 2, g = t & 3;
  bs01[blockIdx.x * 512 + t] = bih[g * 128 + c] + bhh[g * 128 + c];
}
// GAT: Btg[l][n][k] = gatW[l][k][n]
__global__ void k_prepw_gat(const float* __restrict__ gatW, u16* __restrict__ Btg) {
  int idx = blockIdx.x * 256 + threadIdx.x;
  if (idx < NL * 128 * 128) {
    int l = idx >> 14, r = idx & 16383;
    int n = r >> 7, k = r & 127;
    Btg[idx] = f2bf(gatW[(size_t)l * 16384 + k * 128 + n]);
  }
}

// ---------------- input projection (TC timesteps): hbf[tc*N+n,:] = [xs[n]|xd[t0+tc,n]] @ W + b ----
__global__ __launch_bounds__(256) void k_proj(const float* __restrict__ xs,
    const float* __restrict__ xdt, const float* __restrict__ W,
    const float* __restrict__ b, u16* __restrict__ hbf) {
  __shared__ float Ws[24 * HID];
  __shared__ float xin[16][24];
  int tid = threadIdx.x;
  int tc = blockIdx.y;
  for (int i = tid; i < 24 * HID; i += 256) Ws[i] = W[i];
  int n0 = blockIdx.x * 16;
  for (int i = tid; i < 16 * 24; i += 256) {
    int r = i / 24, c = i % 24;
    int n = n0 + r;
    xin[r][c] = (c < SDIM) ? xs[(size_t)n * SDIM + c]
                           : xdt[(size_t)tc * NN * DDIM + (size_t)n * DDIM + (c - SDIM)];
  }
  __syncthreads();
  int ch = tid & 127, rb = (tid >> 7) * 8;
  for (int r = rb; r < rb + 8; r++) {
    float acc = b[ch];
    #pragma unroll
    for (int k = 0; k < 24; k++) acc = fmaf(xin[r][k], Ws[k * HID + ch], acc);
    hbf[((size_t)tc * NN + n0 + r) * HID + ch] = f2bf(acc);
  }
}

#define TBM 128
#define TBN 64
#define TBK 64

// ---------------- GAT GEMM + fused attention-logit epilogue ----------------
// xpbf[M,128] (bf16) = A[M,128] @ Bt^T ; asrc/adst[row,h] = dot(xp_row[h*32:+32], att)
__global__ __launch_bounds__(256) void k_bgemm_gat(const u16* __restrict__ A,
    const u16* __restrict__ Bt, const float* __restrict__ as_,
    const float* __restrict__ ad_, u16* __restrict__ xpbf,
    float* __restrict__ asrc, float* __restrict__ adst, int M) {
  __shared__ u16 As[TBM][TBK + 8];
  __shared__ u16 Bs[TBN][TBK + 8];
  int tid = threadIdx.x;
  int wid = tid >> 6, lane = tid & 63;
  int wr = wid >> 1, wc = wid & 1;
  int lrow = lane & 15, lgrp = lane >> 4;
  int row0 = blockIdx.x * TBM, col0 = blockIdx.y * TBN;
  floatx4 acc[4][2] = {};
  for (int k0 = 0; k0 < 128; k0 += TBK) {
    #pragma unroll
    for (int i = 0; i < 4; i++) {
      int idx = tid + i * 256;
      int r = idx >> 3, g = idx & 7;
      int gr = row0 + r;
      short8 v = {};
      if (gr < M) v = *(const short8*)(A + (size_t)gr * 128 + k0 + g * 8);
      *(short8*)&As[r][g * 8] = v;
    }
    #pragma unroll
    for (int i = 0; i < 2; i++) {
      int idx = tid + i * 256;
      int r = idx >> 3, g = idx & 7;
      *(short8*)&Bs[r][g * 8] = *(const short8*)(Bt + (size_t)(col0 + r) * 128 + k0 + g * 8);
    }
    __syncthreads();
    #pragma unroll
    for (int kk = 0; kk < TBK; kk += 32) {
      short8 bfr[2];
      #pragma unroll
      for (int n = 0; n < 2; n++)
        bfr[n] = *(const short8*)&Bs[wc * 32 + n * 16 + lrow][kk + lgrp * 8];
      #pragma unroll
      for (int m = 0; m < 4; m++) {
        short8 af = *(const short8*)&As[wr * 64 + m * 16 + lrow][kk + lgrp * 8];
        acc[m][0] = __builtin_amdgcn_mfma_f32_16x16x32_bf16(af, bfr[0], acc[m][0], 0, 0, 0);
        acc[m][1] = __builtin_amdgcn_mfma_f32_16x16x32_bf16(af, bfr[1], acc[m][1], 0, 0, 0);
      }
    }
    __syncthreads();
  }
  // epilogue: bf16 xp write + attn logits (wave's 32-col slab = one head)
  int head = (col0 >> 5) + wc;
  float as0 = as_[head * 32 + lrow], as1 = as_[head * 32 + 16 + lrow];
  float ad0 = ad_[head * 32 + lrow], ad1 = ad_[head * 32 + 16 + lrow];
  #pragma unroll
  for (int m = 0; m < 4; m++) {
    #pragma unroll
    for (int r = 0; r < 4; r++) {
      int grow = row0 + wr * 64 + m * 16 + lgrp * 4 + r;
      float v0 = acc[m][0][r], v1 = acc[m][1][r];
      if (grow < M) {
        xpbf[(size_t)grow * HID + col0 + wc * 32 + lrow]      = f2bf(v0);
        xpbf[(size_t)grow * HID + col0 + wc * 32 + 16 + lrow] = f2bf(v1);
      }
      float ps = v0 * as0 + v1 * as1;
      float pd = v0 * ad0 + v1 * ad1;
      #pragma unroll
      for (int off = 1; off < 16; off <<= 1) {
        ps += __shfl_xor(ps, off);
        pd += __shfl_xor(pd, off);
      }
      if (lrow == 0 && grow < M) {
        asrc[grow * HEADS + head] = ps;
        adst[grow * HEADS + head] = pd;
      }
    }
  }
}

// ---------------- GAT aggregation + residual + LayerNorm + ReLU (TC-batched) ----------------
// cooperative 16-edge tile softmax: each lane computes exp for ONE edge of its head;
// weights shared via per-wave LDS row; gather loop is pure fma.
__global__ __launch_bounds__(256) void k_aggr(const u16* __restrict__ xpbf,
    u16* __restrict__ hbf, const float* __restrict__ asrc,
    const float* __restrict__ adst, const int* __restrict__ rowptr,
    const int* __restrict__ col, const float* __restrict__ bias,
    const float* __restrict__ lng, const float* __restrict__ lnb) {
  __shared__ float wls[4][64];
  int wid = threadIdx.x >> 6, lane = threadIdx.x & 63;
  int n = blockIdx.x * 4 + wid;                    // 0 .. TC*NN
  int tc = n / NN;
  int node = n - tc * NN, base = tc * NN;
  int hh = lane >> 4, lrow = lane & 15;
  float ad = adst[n * HEADS + hh];
  float e0 = asrc[n * HEADS + hh] + ad;            // self-loop
  e0 = (e0 > 0.f) ? e0 : 0.2f * e0;
  float m = e0, den = 1.f;
  u32 xv = ((const u32*)(xpbf + (size_t)n * HID))[lane];
  float mg0 = bf2f((u16)(xv & 0xffff)), mg1 = bf2f((u16)(xv >> 16));
  int rs = rowptr[node], re = rowptr[node + 1];
  for (int jt = rs; jt < re; jt += 16) {
    int e = jt + lrow;
    bool valid = e < re;
    int s = 0;
    float ev = -3.0e38f;
    if (valid) {
      s = base + col[e];
      ev = asrc[s * HEADS + hh] + ad;
      ev = (ev > 0.f) ? ev : 0.2f * ev;
    }
    float tm = ev;                                 // tile max within head group
    #pragma unroll
    for (int off = 1; off < 16; off <<= 1) tm = fmaxf(tm, __shfl_xor(tm, off));
    float mn = fmaxf(m, tm);
    float sc = __expf(m - mn);
    float w = valid ? __expf(ev - mn) : 0.f;
    float ws = w;                                  // tile sum within head group
    #pragma unroll
    for (int off = 1; off < 16; off <<= 1) ws += __shfl_xor(ws, off);
    wls[wid][lrow * 4 + hh] = w;                   // bijective: 2-way bank alias (free)
    den = den * sc + ws;
    mg0 *= sc;
    mg1 *= sc;
    m = mn;
    int cnt = min(16, re - jt);
    #pragma unroll 4
    for (int k = 0; k < cnt; k++) {
      int sk = __shfl(s, k, 16);
      float wk = wls[wid][k * 4 + hh];             // broadcast within head group
      u32 xg = ((const u32*)(xpbf + (size_t)sk * HID))[lane];
      mg0 = fmaf(wk, bf2f((u16)(xg & 0xffff)), mg0);
      mg1 = fmaf(wk, bf2f((u16)(xg >> 16)), mg1);
    }
  }
  float inv = 1.f / (den + 1e-16f);
  int c0 = lane * 2;
  size_t hoff = (size_t)n * HID + c0;
  u32 hv = *(const u32*)(hbf + hoff);              // bf16 residual
  float o0 = mg0 * inv + bias[c0]     + bf2f((u16)(hv & 0xffff));
  float o1 = mg1 * inv + bias[c0 + 1] + bf2f((u16)(hv >> 16));
  float s2 = o0 + o1;
  #pragma unroll
  for (int off = 32; off; off >>= 1) s2 += __shfl_xor(s2, off);
  float mu = s2 * (1.f / HID);
  float d0 = o0 - mu, d1 = o1 - mu;
  float v2 = d0 * d0 + d1 * d1;
  #pragma unroll
  for (int off = 32; off; off >>= 1) v2 += __shfl_xor(v2, off);
  float rstd = rsqrtf(v2 * (1.f / HID) + 1e-5f);
  o0 = lng[c0] * d0 * rstd + lnb[c0];
  o1 = lng[c0 + 1] * d1 * rstd + lnb[c0 + 1];
  o0 = fmaxf(o0, 0.f);
  o1 = fmaxf(o1, 0.f);
  *(u32*)(hbf + hoff) = (u32)f2bf(o0) | ((u32)f2bf(o1) << 16);
}

// ---------------- LSTM GEMM + fused gate epilogue ----------------
__global__ __launch_bounds__(256) void k_bgemm_lstm(const u16* __restrict__ A0,
    const u16* __restrict__ A1, const u16* __restrict__ Bt,
    const float* __restrict__ bs, float* __restrict__ cst,
    u16* __restrict__ hout, int M) {
  __shared__ __align__(16) char smem[34816];   // max(As+Bs=27648, zs=128*68*4=34816)
  u16 (*As)[TBK + 8] = (u16(*)[TBK + 8])smem;
  u16 (*Bs)[TBK + 8] = (u16(*)[TBK + 8])(smem + TBM * (TBK + 8) * 2);
  float (*zs)[68] = (float(*)[68])smem;
  int tid = threadIdx.x;
  int wid = tid >> 6, lane = tid & 63;
  int wr = wid >> 1, wc = wid & 1;
  int lrow = lane & 15, lgrp = lane >> 4;
  int row0 = blockIdx.x * TBM, col0 = blockIdx.y * TBN;
  floatx4 acc[4][2] = {};
  for (int k0 = 0; k0 < 256; k0 += TBK) {
    const u16* Ap = (k0 < 128) ? A0 : A1;
    int kb = k0 & 127;
    #pragma unroll
    for (int i = 0; i < 4; i++) {
      int idx = tid + i * 256;
      int r = idx >> 3, g = idx & 7;
      int gr = row0 + r;
      short8 v = {};
      if (gr < M) v = *(const short8*)(Ap + (size_t)gr * 128 + kb + g * 8);
      *(short8*)&As[r][g * 8] = v;
    }
    #pragma unroll
    for (int i = 0; i < 2; i++) {
      int idx = tid + i * 256;
      int r = idx >> 3, g = idx & 7;
      *(short8*)&Bs[r][g * 8] = *(const short8*)(Bt + (size_t)(col0 + r) * 256 + k0 + g * 8);
    }
    __syncthreads();
    #pragma unroll
    for (int kk = 0; kk < TBK; kk += 32) {
      short8 bfr[2];
      #pragma unroll
      for (int n = 0; n < 2; n++)
        bfr[n] = *(const short8*)&Bs[wc * 32 + n * 16 + lrow][kk + lgrp * 8];
      #pragma unroll
      for (int m = 0; m < 4; m++) {
        short8 af = *(const short8*)&As[wr * 64 + m * 16 + lrow][kk + lgrp * 8];
        acc[m][0] = __builtin_amdgcn_mfma_f32_16x16x32_bf16(af, bfr[0], acc[m][0], 0, 0, 0);
        acc[m][1] = __builtin_amdgcn_mfma_f32_16x16x32_bf16(af, bfr[1], acc[m][1], 0, 0, 0);
      }
    }
    __syncthreads();
  }
  // stage z-tile to LDS
  #pragma unroll
  for (int m = 0; m < 4; m++)
    #pragma unroll
    for (int n = 0; n < 2; n++)
      #pragma unroll
      for (int r = 0; r < 4; r++)
        zs[wr * 64 + m * 16 + lgrp * 4 + r][wc * 32 + n * 16 + lrow] = acc[m][n][r];
  __syncthreads();
  // gate epilogue: 128 rows x 16 channels per block
  int ch0 = blockIdx.y * 16;
  #pragma unroll
  for (int it = 0; it < 8; it++) {
    int o = tid + it * 256;
    int r = o >> 4, lc = o & 15;
    int grow = row0 + r;
    if (grow < M) {
      float4 zi = *(float4*)&zs[r][lc * 4];
      int ch = ch0 + lc;
      size_t gi = (size_t)grow * HID + ch;
      float ii = zi.x + bs[4 * ch + 0];
      float ff = zi.y + bs[4 * ch + 1];
      float gg = zi.z + bs[4 * ch + 2];
      float oo = zi.w + bs[4 * ch + 3];
      float si = 1.f / (1.f + __expf(-ii));
      float sf = 1.f / (1.f + __expf(-ff));
      float so = 1.f / (1.f + __expf(-oo));
      float tg = tanhf(gg);
      float cn = sf * cst[gi] + si * tg;
      cst[gi] = cn;
      hout[gi] = f2bf(so * tanhf(cn));
    }
  }
}

// ---------------- output MLP: relu(h1@W1+b1)@W2+b2 ----------------
__global__ __launch_bounds__(64) void k_mlp(const u16* __restrict__ h1,
    const float* __restrict__ W1, const float* __restrict__ b1,
    const float* __restrict__ W2, const float* __restrict__ b2,
    float* __restrict__ out) {
  int n = blockIdx.x, j = threadIdx.x;
  const u16* hr = h1 + (size_t)n * HID;
  float acc = b1[j];
  #pragma unroll 8
  for (int k = 0; k < HID; k++) acc = fmaf(bf2f(hr[k]), W1[(size_t)k * 64 + j], acc);
  acc = fmaxf(acc, 0.f);
  float p = acc * W2[j];
  #pragma unroll
  for (int off = 32; off; off >>= 1) p += __shfl_xor(p, off);
  if (j == 0) out[n] = p + b2[0];
}

extern "C" void kernel_launch(void* const* d_in, const int* in_sizes, int n_in,
                              void* d_out, int out_size, void* d_ws, size_t ws_size,
                              hipStream_t stream) {
  const float* xs    = (const float*)d_in[0];
  const float* xd    = (const float*)d_in[1];
  const int*   ei    = (const int*)d_in[2];
  const float* projW = (const float*)d_in[3];
  const float* projb = (const float*)d_in[4];
  const float* gatW  = (const float*)d_in[5];
  const float* attS  = (const float*)d_in[6];
  const float* attD  = (const float*)d_in[7];
  const float* gatb  = (const float*)d_in[8];
  const float* lng   = (const float*)d_in[9];
  const float* lnb   = (const float*)d_in[10];
  const float* Wih0  = (const float*)d_in[11];
  const float* Whh0  = (const float*)d_in[12];
  const float* bih0  = (const float*)d_in[13];
  const float* bhh0  = (const float*)d_in[14];
  const float* Wih1  = (const float*)d_in[15];
  const float* Whh1  = (const float*)d_in[16];
  const float* bih1  = (const float*)d_in[17];
  const float* bhh1  = (const float*)d_in[18];
  const float* oW1   = (const float*)d_in[19];
  const float* ob1   = (const float*)d_in[20];
  const float* oW2   = (const float*)d_in[21];
  const float* ob2   = (const float*)d_in[22];
  float* out = (float*)d_out;

  // -------- workspace layout (~75 MB) --------
  char* w = (char*)d_ws;
  size_t off = 0;
  auto alloc = [&](size_t bytes) { void* p = w + off; off += (bytes + 255) & ~(size_t)255; return p; };
  u16*   hbf   = (u16*)  alloc((size_t)TC * NN * HID * 2);   // bf16 h (GEMM A + residual)
  u16*   xpbf  = (u16*)  alloc((size_t)TC * NN * HID * 2);   // bf16 xp
  float* asrc  = (float*)alloc((size_t)TC * NN * HEADS * 4);
  float* adst  = (float*)alloc((size_t)TC * NN * HEADS * 4);
  float* c01   = (float*)alloc((size_t)2 * NN * HID * 4);    // c0,c1
  float* c0 = c01, *c1 = c01 + (size_t)NN * HID;
  u16*   h0p   = (u16*)  alloc((size_t)2 * NN * HID * 2);    // h0 ping-pong
  u16*   h1p   = (u16*)  alloc((size_t)2 * NN * HID * 2);    // h1 ping-pong
  u16*   h0buf[2] = { h0p, h0p + (size_t)NN * HID };
  u16*   h1buf[2] = { h1p, h1p + (size_t)NN * HID };
  u16*   Wc0bf = (u16*)alloc((size_t)512 * 256 * 2);
  u16*   Wc1bf = (u16*)alloc((size_t)512 * 256 * 2);
  float* bs01  = (float*)alloc((size_t)1024 * 4);
  float* bs0 = bs01, *bs1 = bs01 + 512;
  u16*   gatWbf= (u16*)alloc((size_t)NL * 128 * 128 * 2);
  int* cnt    = (int*)alloc((size_t)NN * 4);
  int* rowptr = (int*)alloc((size_t)(NN + 1) * 4);
  int* cursor = (int*)alloc((size_t)NN * 4);
  int* col    = (int*)alloc((size_t)NE * 4);

  const int* esrc = ei;
  const int* edst = ei + NE;

  // -------- CSR (edge_index identical across t and layers) --------
  hipMemsetAsync(cnt, 0, (size_t)NN * 4, stream);
  k_count<<<(NE + 255) / 256, 256, 0, stream>>>(edst, cnt);
  k_scan<<<1, 1024, 0, stream>>>(cnt, rowptr, cursor);
  k_fill<<<(NE + 255) / 256, 256, 0, stream>>>(esrc, edst, cursor, col);

  // -------- weight/bias prep + state init --------
  k_prepw_lstm<<<(512 * 256) / 256, 256, 0, stream>>>(Wih0, Whh0, Wc0bf);
  k_prepw_lstm<<<(512 * 256) / 256, 256, 0, stream>>>(Wih1, Whh1, Wc1bf);
  k_prepb<<<2, 512, 0, stream>>>(bih0, bhh0, bih1, bhh1, bs01);
  k_prepw_gat<<<(NL * 128 * 128) / 256, 256, 0, stream>>>(gatW, gatWbf);
  hipMemsetAsync(c01, 0, (size_t)2 * NN * HID * 4, stream);
  hipMemsetAsync(h0buf[0], 0, (size_t)NN * HID * 2, stream);
  hipMemsetAsync(h1buf[0], 0, (size_t)NN * HID * 2, stream);

  // -------- per chunk: batched GNN (TC timesteps), then sequential LSTM --------
  const int gx  = (NN + TBM - 1) / TBM;             // 157
  const int gx2 = (TC * NN + TBM - 1) / TBM;        // 625
  for (int tcb = 0; tcb < TT / TC; tcb++) {
    k_proj<<<dim3(NN / 16, TC), 256, 0, stream>>>(
        xs, xd + (size_t)(tcb * TC) * NN * DDIM, projW, projb, hbf);
    for (int l = 0; l < NL; l++) {
      k_bgemm_gat<<<dim3(gx2, 2), 256, 0, stream>>>(
          hbf, gatWbf + (size_t)l * 128 * 128,
          attS + l * HEADS * DPH, attD + l * HEADS * DPH,
          xpbf, asrc, adst, TC * NN);
      k_aggr<<<TC * NN / 4, 256, 0, stream>>>(
          xpbf, hbf, asrc, adst, rowptr, col, gatb + (size_t)l * HID,
          lng + (size_t)l * HID, lnb + (size_t)l * HID);
    }
    for (int s2 = 0; s2 < TC; s2++) {
      int t = tcb * TC + s2;
      int pi = t & 1;
      k_bgemm_lstm<<<dim3(gx, 8), 256, 0, stream>>>(
          hbf + (size_t)s2 * NN * HID, h0buf[pi], Wc0bf, bs0, c0, h0buf[pi ^ 1], NN);
      k_bgemm_lstm<<<dim3(gx, 8), 256, 0, stream>>>(
          h0buf[pi ^ 1], h1buf[pi], Wc1bf, bs1, c1, h1buf[pi ^ 1], NN);
    }
  }

  // TT even -> final h1 lives in h1buf[0]
  k_mlp<<<NN, 64, 0, stream>>>(h1buf[0], oW1, ob1, oW2, ob2, out);
}

// Round 10
// 3499.099 us; speedup vs baseline: 1.1525x; 1.1525x over previous
//
#include <hip/hip_runtime.h>
#include <hip/hip_bf16.h>
#include <math.h>

#define NN   20000
#define NE   320000
#define TT   24
#define SDIM 16
#define DDIM 8
#define HID  128
#define HEADS 4
#define DPH  32
#define NL   3
#define TC   4          // timesteps batched per GNN chunk (divides TT)

typedef unsigned short u16;
typedef unsigned int   u32;
typedef __attribute__((ext_vector_type(8))) short  short8;
typedef __attribute__((ext_vector_type(4))) float  floatx4;

__device__ __forceinline__ u16 f2bf(float x) {          // round-to-nearest-even
  u32 u = __float_as_uint(x);
  return (u16)((u + 0x7fff + ((u >> 16) & 1)) >> 16);
}
__device__ __forceinline__ float bf2f(u16 b) {
  return __uint_as_float(((u32)b) << 16);
}

// ---------------- CSR build (group edges by dst) ----------------
__global__ void k_count(const int* __restrict__ dst, int* __restrict__ cnt) {
  int e = blockIdx.x * 256 + threadIdx.x;
  if (e < NE) atomicAdd(&cnt[dst[e]], 1);
}

__global__ __launch_bounds__(1024) void k_scan(const int* __restrict__ cnt,
    int* __restrict__ rowptr, int* __restrict__ cursor) {
  __shared__ int sh[1024];
  int tid = threadIdx.x;
  const int CH = 20;                      // 1024*20 >= NN
  int base = tid * CH;
  int local[CH];
  int s = 0;
  #pragma unroll
  for (int i = 0; i < CH; i++) {
    int idx = base + i;
    int v = (idx < NN) ? cnt[idx] : 0;
    local[i] = s;
    s += v;
  }
  sh[tid] = s;
  __syncthreads();
  for (int off = 1; off < 1024; off <<= 1) {
    int tv = (tid >= off) ? sh[tid - off] : 0;
    __syncthreads();
    sh[tid] += tv;
    __syncthreads();
  }
  int pre = (tid > 0) ? sh[tid - 1] : 0;
  #pragma unroll
  for (int i = 0; i < CH; i++) {
    int idx = base + i;
    if (idx < NN) { int e = pre + local[i]; rowptr[idx] = e; cursor[idx] = e; }
  }
  if (tid == 1023) rowptr[NN] = sh[1023];
}

__global__ void k_fill(const int* __restrict__ src, const int* __restrict__ dst,
    int* __restrict__ cursor, int* __restrict__ col) {
  int e = blockIdx.x * 256 + threadIdx.x;
  if (e < NE) {
    int pos = atomicAdd(&cursor[dst[e]], 1);
    col[pos] = src[e];
  }
}

// ---------------- weight prep ----------------
// LSTM weights, GATE-INTERLEAVED: Bt[4c+g][k] = W[g*128+c][k], W = [Wih | Whh]
__global__ void k_prepw_lstm(const float* __restrict__ Wih, const float* __restrict__ Whh,
    u16* __restrict__ Bt) {
  int idx = blockIdx.x * 256 + threadIdx.x;
  if (idx < 512 * 256) {
    int jp = idx >> 8, k = idx & 255;
    int c = jp >> 2, g = jp & 3;
    int j = g * 128 + c;
    float v = (k < 128) ? Wih[(size_t)j * 128 + k] : Whh[(size_t)j * 128 + (k - 128)];
    Bt[idx] = f2bf(v);
  }
}
// combined bias, gate-interleaved: bs[4c+g] = bih[g*128+c] + bhh[g*128+c]; 2 cells
__global__ void k_prepb(const float* __restrict__ bih0, const float* __restrict__ bhh0,
    const float* __restrict__ bih1, const float* __restrict__ bhh1,
    float* __restrict__ bs01) {
  int t = threadIdx.x;               // 512 per block, blockIdx.x = cell
  const float* bih = blockIdx.x ? bih1 : bih0;
  const float* bhh = blockIdx.x ? bhh1 : bhh0;
  int c = t >> 2, g = t & 3;
  bs01[blockIdx.x * 512 + t] = bih[g * 128 + c] + bhh[g * 128 + c];
}
// GAT: Btg[l][n][k] = gatW[l][k][n]
__global__ void k_prepw_gat(const float* __restrict__ gatW, u16* __restrict__ Btg) {
  int idx = blockIdx.x * 256 + threadIdx.x;
  if (idx < NL * 128 * 128) {
    int l = idx >> 14, r = idx & 16383;
    int n = r >> 7, k = r & 127;
    Btg[idx] = f2bf(gatW[(size_t)l * 16384 + k * 128 + n]);
  }
}

// ---------------- input projection (TC timesteps): hbf[tc*N+n,:] = [xs[n]|xd[t0+tc,n]] @ W + b ----
__global__ __launch_bounds__(256) void k_proj(const float* __restrict__ xs,
    const float* __restrict__ xdt, const float* __restrict__ W,
    const float* __restrict__ b, u16* __restrict__ hbf) {
  __shared__ float Ws[24 * HID];
  __shared__ float xin[16][24];
  int tid = threadIdx.x;
  int tc = blockIdx.y;
  for (int i = tid; i < 24 * HID; i += 256) Ws[i] = W[i];
  int n0 = blockIdx.x * 16;
  for (int i = tid; i < 16 * 24; i += 256) {
    int r = i / 24, c = i % 24;
    int n = n0 + r;
    xin[r][c] = (c < SDIM) ? xs[(size_t)n * SDIM + c]
                           : xdt[(size_t)tc * NN * DDIM + (size_t)n * DDIM + (c - SDIM)];
  }
  __syncthreads();
  int ch = tid & 127, rb = (tid >> 7) * 8;
  for (int r = rb; r < rb + 8; r++) {
    float acc = b[ch];
    #pragma unroll
    for (int k = 0; k < 24; k++) acc = fmaf(xin[r][k], Ws[k * HID + ch], acc);
    hbf[((size_t)tc * NN + n0 + r) * HID + ch] = f2bf(acc);
  }
}

#define TBM 128
#define TBN 64
#define TBK 64

// ---------------- GAT GEMM + fused attention-logit epilogue ----------------
// xpbf[M,128] (bf16) = A[M,128] @ Bt^T ; asrc/adst[row,h] = dot(xp_row[h*32:+32], att)
__global__ __launch_bounds__(256) void k_bgemm_gat(const u16* __restrict__ A,
    const u16* __restrict__ Bt, const float* __restrict__ as_,
    const float* __restrict__ ad_, u16* __restrict__ xpbf,
    float* __restrict__ asrc, float* __restrict__ adst, int M) {
  __shared__ u16 As[TBM][TBK + 8];
  __shared__ u16 Bs[TBN][TBK + 8];
  int tid = threadIdx.x;
  int wid = tid >> 6, lane = tid & 63;
  int wr = wid >> 1, wc = wid & 1;
  int lrow = lane & 15, lgrp = lane >> 4;
  int row0 = blockIdx.x * TBM, col0 = blockIdx.y * TBN;
  floatx4 acc[4][2] = {};
  for (int k0 = 0; k0 < 128; k0 += TBK) {
    #pragma unroll
    for (int i = 0; i < 4; i++) {
      int idx = tid + i * 256;
      int r = idx >> 3, g = idx & 7;
      int gr = row0 + r;
      short8 v = {};
      if (gr < M) v = *(const short8*)(A + (size_t)gr * 128 + k0 + g * 8);
      *(short8*)&As[r][g * 8] = v;
    }
    #pragma unroll
    for (int i = 0; i < 2; i++) {
      int idx = tid + i * 256;
      int r = idx >> 3, g = idx & 7;
      *(short8*)&Bs[r][g * 8] = *(const short8*)(Bt + (size_t)(col0 + r) * 128 + k0 + g * 8);
    }
    __syncthreads();
    #pragma unroll
    for (int kk = 0; kk < TBK; kk += 32) {
      short8 bfr[2];
      #pragma unroll
      for (int n = 0; n < 2; n++)
        bfr[n] = *(const short8*)&Bs[wc * 32 + n * 16 + lrow][kk + lgrp * 8];
      #pragma unroll
      for (int m = 0; m < 4; m++) {
        short8 af = *(const short8*)&As[wr * 64 + m * 16 + lrow][kk + lgrp * 8];
        acc[m][0] = __builtin_amdgcn_mfma_f32_16x16x32_bf16(af, bfr[0], acc[m][0], 0, 0, 0);
        acc[m][1] = __builtin_amdgcn_mfma_f32_16x16x32_bf16(af, bfr[1], acc[m][1], 0, 0, 0);
      }
    }
    __syncthreads();
  }
  // epilogue: bf16 xp write + attn logits (wave's 32-col slab = one head)
  int head = (col0 >> 5) + wc;
  float as0 = as_[head * 32 + lrow], as1 = as_[head * 32 + 16 + lrow];
  float ad0 = ad_[head * 32 + lrow], ad1 = ad_[head * 32 + 16 + lrow];
  #pragma unroll
  for (int m = 0; m < 4; m++) {
    #pragma unroll
    for (int r = 0; r < 4; r++) {
      int grow = row0 + wr * 64 + m * 16 + lgrp * 4 + r;
      float v0 = acc[m][0][r], v1 = acc[m][1][r];
      if (grow < M) {
        xpbf[(size_t)grow * HID + col0 + wc * 32 + lrow]      = f2bf(v0);
        xpbf[(size_t)grow * HID + col0 + wc * 32 + 16 + lrow] = f2bf(v1);
      }
      float ps = v0 * as0 + v1 * as1;
      float pd = v0 * ad0 + v1 * ad1;
      #pragma unroll
      for (int off = 1; off < 16; off <<= 1) {
        ps += __shfl_xor(ps, off);
        pd += __shfl_xor(pd, off);
      }
      if (lrow == 0 && grow < M) {
        asrc[grow * HEADS + head] = ps;
        adst[grow * HEADS + head] = pd;
      }
    }
  }
}

// ---------------- GAT aggregation + residual + LayerNorm + ReLU (TC-batched) ----------------
// MAX-FREE softmax (logits are O(1); clamp at 80 guards overflow). No cross-edge
// dependency: 4 independent accumulator sets, merged at the end.
__global__ __launch_bounds__(256) void k_aggr(const u16* __restrict__ xpbf,
    u16* __restrict__ hbf, const float* __restrict__ asrc,
    const float* __restrict__ adst, const int* __restrict__ rowptr,
    const int* __restrict__ col, const float* __restrict__ bias,
    const float* __restrict__ lng, const float* __restrict__ lnb) {
  int wid = threadIdx.x >> 6, lane = threadIdx.x & 63;
  int n = blockIdx.x * 4 + wid;                    // 0 .. TC*NN
  int tc = n / NN;
  int node = n - tc * NN, base = tc * NN;
  int hh = lane >> 4;
  float ad = adst[n * HEADS + hh];
  float e0 = asrc[n * HEADS + hh] + ad;            // self-loop
  e0 = (e0 > 0.f) ? e0 : 0.2f * e0;
  float w0 = __expf(fminf(e0, 80.f));
  u32 xv = ((const u32*)(xpbf + (size_t)n * HID))[lane];
  float den0 = w0, den1 = 0.f, den2 = 0.f, den3 = 0.f;
  float p00 = w0 * bf2f((u16)(xv & 0xffff)), p10 = 0.f, p20 = 0.f, p30 = 0.f;
  float p01 = w0 * bf2f((u16)(xv >> 16)),    p11 = 0.f, p21 = 0.f, p31 = 0.f;
  int rs = rowptr[node], re = rowptr[node + 1];
  int j = rs;
  for (; j + 4 <= re; j += 4) {                    // independent 4-edge unroll
    int s0 = base + col[j],     s1 = base + col[j + 1];
    int s2 = base + col[j + 2], s3 = base + col[j + 3];
    float ev0 = asrc[s0 * HEADS + hh] + ad;
    float ev1 = asrc[s1 * HEADS + hh] + ad;
    float ev2 = asrc[s2 * HEADS + hh] + ad;
    float ev3 = asrc[s3 * HEADS + hh] + ad;
    u32 x0 = ((const u32*)(xpbf + (size_t)s0 * HID))[lane];
    u32 x1 = ((const u32*)(xpbf + (size_t)s1 * HID))[lane];
    u32 x2 = ((const u32*)(xpbf + (size_t)s2 * HID))[lane];
    u32 x3 = ((const u32*)(xpbf + (size_t)s3 * HID))[lane];
    ev0 = (ev0 > 0.f) ? ev0 : 0.2f * ev0;
    ev1 = (ev1 > 0.f) ? ev1 : 0.2f * ev1;
    ev2 = (ev2 > 0.f) ? ev2 : 0.2f * ev2;
    ev3 = (ev3 > 0.f) ? ev3 : 0.2f * ev3;
    float w0e = __expf(fminf(ev0, 80.f));
    float w1e = __expf(fminf(ev1, 80.f));
    float w2e = __expf(fminf(ev2, 80.f));
    float w3e = __expf(fminf(ev3, 80.f));
    den0 += w0e; den1 += w1e; den2 += w2e; den3 += w3e;
    p00 = fmaf(w0e, bf2f((u16)(x0 & 0xffff)), p00);
    p10 = fmaf(w1e, bf2f((u16)(x1 & 0xffff)), p10);
    p20 = fmaf(w2e, bf2f((u16)(x2 & 0xffff)), p20);
    p30 = fmaf(w3e, bf2f((u16)(x3 & 0xffff)), p30);
    p01 = fmaf(w0e, bf2f((u16)(x0 >> 16)), p01);
    p11 = fmaf(w1e, bf2f((u16)(x1 >> 16)), p11);
    p21 = fmaf(w2e, bf2f((u16)(x2 >> 16)), p21);
    p31 = fmaf(w3e, bf2f((u16)(x3 >> 16)), p31);
  }
  for (; j < re; j++) {
    int s0 = base + col[j];
    float ev = asrc[s0 * HEADS + hh] + ad;
    ev = (ev > 0.f) ? ev : 0.2f * ev;
    u32 x0 = ((const u32*)(xpbf + (size_t)s0 * HID))[lane];
    float w = __expf(fminf(ev, 80.f));
    den0 += w;
    p00 = fmaf(w, bf2f((u16)(x0 & 0xffff)), p00);
    p01 = fmaf(w, bf2f((u16)(x0 >> 16)), p01);
  }
  float den = (den0 + den1) + (den2 + den3);
  float mg0 = (p00 + p10) + (p20 + p30);
  float mg1 = (p01 + p11) + (p21 + p31);
  float inv = 1.f / (den + 1e-16f);
  int c0 = lane * 2;
  size_t hoff = (size_t)n * HID + c0;
  u32 hv = *(const u32*)(hbf + hoff);              // bf16 residual
  float o0 = mg0 * inv + bias[c0]     + bf2f((u16)(hv & 0xffff));
  float o1 = mg1 * inv + bias[c0 + 1] + bf2f((u16)(hv >> 16));
  float s2 = o0 + o1;
  #pragma unroll
  for (int off = 32; off; off >>= 1) s2 += __shfl_xor(s2, off);
  float mu = s2 * (1.f / HID);
  float d0 = o0 - mu, d1 = o1 - mu;
  float v2 = d0 * d0 + d1 * d1;
  #pragma unroll
  for (int off = 32; off; off >>= 1) v2 += __shfl_xor(v2, off);
  float rstd = rsqrtf(v2 * (1.f / HID) + 1e-5f);
  o0 = lng[c0] * d0 * rstd + lnb[c0];
  o1 = lng[c0 + 1] * d1 * rstd + lnb[c0 + 1];
  o0 = fmaxf(o0, 0.f);
  o1 = fmaxf(o1, 0.f);
  *(u32*)(hbf + hoff) = (u32)f2bf(o0) | ((u32)f2bf(o1) << 16);
}

// ---------------- LSTM GEMM + fused gate epilogue ----------------
__global__ __launch_bounds__(256) void k_bgemm_lstm(const u16* __restrict__ A0,
    const u16* __restrict__ A1, const u16* __restrict__ Bt,
    const float* __restrict__ bs, float* __restrict__ cst,
    u16* __restrict__ hout, int M) {
  __shared__ __align__(16) char smem[34816];   // max(As+Bs=27648, zs=128*68*4=34816)
  u16 (*As)[TBK + 8] = (u16(*)[TBK + 8])smem;
  u16 (*Bs)[TBK + 8] = (u16(*)[TBK + 8])(smem + TBM * (TBK + 8) * 2);
  float (*zs)[68] = (float(*)[68])smem;
  int tid = threadIdx.x;
  int wid = tid >> 6, lane = tid & 63;
  int wr = wid >> 1, wc = wid & 1;
  int lrow = lane & 15, lgrp = lane >> 4;
  int row0 = blockIdx.x * TBM, col0 = blockIdx.y * TBN;
  floatx4 acc[4][2] = {};
  for (int k0 = 0; k0 < 256; k0 += TBK) {
    const u16* Ap = (k0 < 128) ? A0 : A1;
    int kb = k0 & 127;
    #pragma unroll
    for (int i = 0; i < 4; i++) {
      int idx = tid + i * 256;
      int r = idx >> 3, g = idx & 7;
      int gr = row0 + r;
      short8 v = {};
      if (gr < M) v = *(const short8*)(Ap + (size_t)gr * 128 + kb + g * 8);
      *(short8*)&As[r][g * 8] = v;
    }
    #pragma unroll
    for (int i = 0; i < 2; i++) {
      int idx = tid + i * 256;
      int r = idx >> 3, g = idx & 7;
      *(short8*)&Bs[r][g * 8] = *(const short8*)(Bt + (size_t)(col0 + r) * 256 + k0 + g * 8);
    }
    __syncthreads();
    #pragma unroll
    for (int kk = 0; kk < TBK; kk += 32) {
      short8 bfr[2];
      #pragma unroll
      for (int n = 0; n < 2; n++)
        bfr[n] = *(const short8*)&Bs[wc * 32 + n * 16 + lrow][kk + lgrp * 8];
      #pragma unroll
      for (int m = 0; m < 4; m++) {
        short8 af = *(const short8*)&As[wr * 64 + m * 16 + lrow][kk + lgrp * 8];
        acc[m][0] = __builtin_amdgcn_mfma_f32_16x16x32_bf16(af, bfr[0], acc[m][0], 0, 0, 0);
        acc[m][1] = __builtin_amdgcn_mfma_f32_16x16x32_bf16(af, bfr[1], acc[m][1], 0, 0, 0);
      }
    }
    __syncthreads();
  }
  // stage z-tile to LDS
  #pragma unroll
  for (int m = 0; m < 4; m++)
    #pragma unroll
    for (int n = 0; n < 2; n++)
      #pragma unroll
      for (int r = 0; r < 4; r++)
        zs[wr * 64 + m * 16 + lgrp * 4 + r][wc * 32 + n * 16 + lrow] = acc[m][n][r];
  __syncthreads();
  // gate epilogue: 128 rows x 16 channels per block
  int ch0 = blockIdx.y * 16;
  #pragma unroll
  for (int it = 0; it < 8; it++) {
    int o = tid + it * 256;
    int r = o >> 4, lc = o & 15;
    int grow = row0 + r;
    if (grow < M) {
      float4 zi = *(float4*)&zs[r][lc * 4];
      int ch = ch0 + lc;
      size_t gi = (size_t)grow * HID + ch;
      float ii = zi.x + bs[4 * ch + 0];
      float ff = zi.y + bs[4 * ch + 1];
      float gg = zi.z + bs[4 * ch + 2];
      float oo = zi.w + bs[4 * ch + 3];
      float si = 1.f / (1.f + __expf(-ii));
      float sf = 1.f / (1.f + __expf(-ff));
      float so = 1.f / (1.f + __expf(-oo));
      float tg = tanhf(gg);
      float cn = sf * cst[gi] + si * tg;
      cst[gi] = cn;
      hout[gi] = f2bf(so * tanhf(cn));
    }
  }
}

// ---------------- output MLP: relu(h1@W1+b1)@W2+b2 ----------------
__global__ __launch_bounds__(64) void k_mlp(const u16* __restrict__ h1,
    const float* __restrict__ W1, const float* __restrict__ b1,
    const float* __restrict__ W2, const float* __restrict__ b2,
    float* __restrict__ out) {
  int n = blockIdx.x, j = threadIdx.x;
  const u16* hr = h1 + (size_t)n * HID;
  float acc = b1[j];
  #pragma unroll 8
  for (int k = 0; k < HID; k++) acc = fmaf(bf2f(hr[k]), W1[(size_t)k * 64 + j], acc);
  acc = fmaxf(acc, 0.f);
  float p = acc * W2[j];
  #pragma unroll
  for (int off = 32; off; off >>= 1) p += __shfl_xor(p, off);
  if (j == 0) out[n] = p + b2[0];
}

extern "C" void kernel_launch(void* const* d_in, const int* in_sizes, int n_in,
                              void* d_out, int out_size, void* d_ws, size_t ws_size,
                              hipStream_t stream) {
  const float* xs    = (const float*)d_in[0];
  const float* xd    = (const float*)d_in[1];
  const int*   ei    = (const int*)d_in[2];
  const float* projW = (const float*)d_in[3];
  const float* projb = (const float*)d_in[4];
  const float* gatW  = (const float*)d_in[5];
  const float* attS  = (const float*)d_in[6];
  const float* attD  = (const float*)d_in[7];
  const float* gatb  = (const float*)d_in[8];
  const float* lng   = (const float*)d_in[9];
  const float* lnb   = (const float*)d_in[10];
  const float* Wih0  = (const float*)d_in[11];
  const float* Whh0  = (const float*)d_in[12];
  const float* bih0  = (const float*)d_in[13];
  const float* bhh0  = (const float*)d_in[14];
  const float* Wih1  = (const float*)d_in[15];
  const float* Whh1  = (const float*)d_in[16];
  const float* bih1  = (const float*)d_in[17];
  const float* bhh1  = (const float*)d_in[18];
  const float* oW1   = (const float*)d_in[19];
  const float* ob1   = (const float*)d_in[20];
  const float* oW2   = (const float*)d_in[21];
  const float* ob2   = (const float*)d_in[22];
  float* out = (float*)d_out;

  // -------- workspace layout (~75 MB) --------
  char* w = (char*)d_ws;
  size_t off = 0;
  auto alloc = [&](size_t bytes) { void* p = w + off; off += (bytes + 255) & ~(size_t)255; return p; };
  u16*   hbf   = (u16*)  alloc((size_t)TC * NN * HID * 2);   // bf16 h (GEMM A + residual)
  u16*   xpbf  = (u16*)  alloc((size_t)TC * NN * HID * 2);   // bf16 xp
  float* asrc  = (float*)alloc((size_t)TC * NN * HEADS * 4);
  float* adst  = (float*)alloc((size_t)TC * NN * HEADS * 4);
  float* c01   = (float*)alloc((size_t)2 * NN * HID * 4);    // c0,c1
  float* c0 = c01, *c1 = c01 + (size_t)NN * HID;
  u16*   h0p   = (u16*)  alloc((size_t)2 * NN * HID * 2);    // h0 ping-pong
  u16*   h1p   = (u16*)  alloc((size_t)2 * NN * HID * 2);    // h1 ping-pong
  u16*   h0buf[2] = { h0p, h0p + (size_t)NN * HID };
  u16*   h1buf[2] = { h1p, h1p + (size_t)NN * HID };
  u16*   Wc0bf = (u16*)alloc((size_t)512 * 256 * 2);
  u16*   Wc1bf = (u16*)alloc((size_t)512 * 256 * 2);
  float* bs01  = (float*)alloc((size_t)1024 * 4);
  float* bs0 = bs01, *bs1 = bs01 + 512;
  u16*   gatWbf= (u16*)alloc((size_t)NL * 128 * 128 * 2);
  int* cnt    = (int*)alloc((size_t)NN * 4);
  int* rowptr = (int*)alloc((size_t)(NN + 1) * 4);
  int* cursor = (int*)alloc((size_t)NN * 4);
  int* col    = (int*)alloc((size_t)NE * 4);

  const int* esrc = ei;
  const int* edst = ei + NE;

  // -------- CSR (edge_index identical across t and layers) --------
  hipMemsetAsync(cnt, 0, (size_t)NN * 4, stream);
  k_count<<<(NE + 255) / 256, 256, 0, stream>>>(edst, cnt);
  k_scan<<<1, 1024, 0, stream>>>(cnt, rowptr, cursor);
  k_fill<<<(NE + 255) / 256, 256, 0, stream>>>(esrc, edst, cursor, col);

  // -------- weight/bias prep + state init --------
  k_prepw_lstm<<<(512 * 256) / 256, 256, 0, stream>>>(Wih0, Whh0, Wc0bf);
  k_prepw_lstm<<<(512 * 256) / 256, 256, 0, stream>>>(Wih1, Whh1, Wc1bf);
  k_prepb<<<2, 512, 0, stream>>>(bih0, bhh0, bih1, bhh1, bs01);
  k_prepw_gat<<<(NL * 128 * 128) / 256, 256, 0, stream>>>(gatW, gatWbf);
  hipMemsetAsync(c01, 0, (size_t)2 * NN * HID * 4, stream);
  hipMemsetAsync(h0buf[0], 0, (size_t)NN * HID * 2, stream);
  hipMemsetAsync(h1buf[0], 0, (size_t)NN * HID * 2, stream);

  // -------- per chunk: batched GNN (TC timesteps), then sequential LSTM --------
  const int gx  = (NN + TBM - 1) / TBM;             // 157
  const int gx2 = (TC * NN + TBM - 1) / TBM;        // 625
  for (int tcb = 0; tcb < TT / TC; tcb++) {
    k_proj<<<dim3(NN / 16, TC), 256, 0, stream>>>(
        xs, xd + (size_t)(tcb * TC) * NN * DDIM, projW, projb, hbf);
    for (int l = 0; l < NL; l++) {
      k_bgemm_gat<<<dim3(gx2, 2), 256, 0, stream>>>(
          hbf, gatWbf + (size_t)l * 128 * 128,
          attS + l * HEADS * DPH, attD + l * HEADS * DPH,
          xpbf, asrc, adst, TC * NN);
      k_aggr<<<TC * NN / 4, 256, 0, stream>>>(
          xpbf, hbf, asrc, adst, rowptr, col, gatb + (size_t)l * HID,
          lng + (size_t)l * HID, lnb + (size_t)l * HID);
    }
    for (int s2 = 0; s2 < TC; s2++) {
      int t = tcb * TC + s2;
      int pi = t & 1;
      k_bgemm_lstm<<<dim3(gx, 8), 256, 0, stream>>>(
          hbf + (size_t)s2 * NN * HID, h0buf[pi], Wc0bf, bs0, c0, h0buf[pi ^ 1], NN);
      k_bgemm_lstm<<<dim3(gx, 8), 256, 0, stream>>>(
          h0buf[pi ^ 1], h1buf[pi], Wc1bf, bs1, c1, h1buf[pi ^ 1], NN);
    }
  }

  // TT even -> final h1 lives in h1buf[0]
  k_mlp<<<NN, 64, 0, stream>>>(h1buf[0], oW1, ob1, oW2, ob2, out);
}

// Round 11
// 3318.111 us; speedup vs baseline: 1.2153x; 1.0545x over previous
//
#include <hip/hip_runtime.h>
#include <hip/hip_bf16.h>
#include <math.h>

#define NN   20000
#define NE   320000
#define TT   24
#define SDIM 16
#define DDIM 8
#define HID  128
#define HEADS 4
#define DPH  32
#define NL   3
#define TC   4          // timesteps batched per GNN chunk (divides TT)

typedef unsigned short u16;
typedef unsigned int   u32;
typedef __attribute__((ext_vector_type(8))) short  short8;
typedef __attribute__((ext_vector_type(4))) float  floatx4;

__device__ __forceinline__ u16 f2bf(float x) {          // round-to-nearest-even
  u32 u = __float_as_uint(x);
  return (u16)((u + 0x7fff + ((u >> 16) & 1)) >> 16);
}
__device__ __forceinline__ float bf2f(u16 b) {
  return __uint_as_float(((u32)b) << 16);
}

// ---------------- CSR build (group edges by dst) ----------------
__global__ void k_count(const int* __restrict__ dst, int* __restrict__ cnt) {
  int e = blockIdx.x * 256 + threadIdx.x;
  if (e < NE) atomicAdd(&cnt[dst[e]], 1);
}

__global__ __launch_bounds__(1024) void k_scan(const int* __restrict__ cnt,
    int* __restrict__ rowptr, int* __restrict__ cursor) {
  __shared__ int sh[1024];
  int tid = threadIdx.x;
  const int CH = 20;                      // 1024*20 >= NN
  int base = tid * CH;
  int local[CH];
  int s = 0;
  #pragma unroll
  for (int i = 0; i < CH; i++) {
    int idx = base + i;
    int v = (idx < NN) ? cnt[idx] : 0;
    local[i] = s;
    s += v;
  }
  sh[tid] = s;
  __syncthreads();
  for (int off = 1; off < 1024; off <<= 1) {
    int tv = (tid >= off) ? sh[tid - off] : 0;
    __syncthreads();
    sh[tid] += tv;
    __syncthreads();
  }
  int pre = (tid > 0) ? sh[tid - 1] : 0;
  #pragma unroll
  for (int i = 0; i < CH; i++) {
    int idx = base + i;
    if (idx < NN) { int e = pre + local[i]; rowptr[idx] = e; cursor[idx] = e; }
  }
  if (tid == 1023) rowptr[NN] = sh[1023];
}

__global__ void k_fill(const int* __restrict__ src, const int* __restrict__ dst,
    int* __restrict__ cursor, int* __restrict__ col, int* __restrict__ row) {
  int e = blockIdx.x * 256 + threadIdx.x;
  if (e < NE) {
    int d = dst[e];
    int pos = atomicAdd(&cursor[d], 1);
    col[pos] = src[e];
    row[pos] = d;
  }
}

// ---------------- weight prep ----------------
// LSTM weights, GATE-INTERLEAVED: Bt[4c+g][k] = W[g*128+c][k], W = [Wih | Whh]
__global__ void k_prepw_lstm(const float* __restrict__ Wih, const float* __restrict__ Whh,
    u16* __restrict__ Bt) {
  int idx = blockIdx.x * 256 + threadIdx.x;
  if (idx < 512 * 256) {
    int jp = idx >> 8, k = idx & 255;
    int c = jp >> 2, g = jp & 3;
    int j = g * 128 + c;
    float v = (k < 128) ? Wih[(size_t)j * 128 + k] : Whh[(size_t)j * 128 + (k - 128)];
    Bt[idx] = f2bf(v);
  }
}
// combined bias, gate-interleaved: bs[4c+g] = bih[g*128+c] + bhh[g*128+c]; 2 cells
__global__ void k_prepb(const float* __restrict__ bih0, const float* __restrict__ bhh0,
    const float* __restrict__ bih1, const float* __restrict__ bhh1,
    float* __restrict__ bs01) {
  int t = threadIdx.x;               // 512 per block, blockIdx.x = cell
  const float* bih = blockIdx.x ? bih1 : bih0;
  const float* bhh = blockIdx.x ? bhh1 : bhh0;
  int c = t >> 2, g = t & 3;
  bs01[blockIdx.x * 512 + t] = bih[g * 128 + c] + bhh[g * 128 + c];
}
// GAT: Btg[l][n][k] = gatW[l][k][n]
__global__ void k_prepw_gat(const float* __restrict__ gatW, u16* __restrict__ Btg) {
  int idx = blockIdx.x * 256 + threadIdx.x;
  if (idx < NL * 128 * 128) {
    int l = idx >> 14, r = idx & 16383;
    int n = r >> 7, k = r & 127;
    Btg[idx] = f2bf(gatW[(size_t)l * 16384 + k * 128 + n]);
  }
}

// ---------------- input projection (TC timesteps) ----------------
__global__ __launch_bounds__(256) void k_proj(const float* __restrict__ xs,
    const float* __restrict__ xdt, const float* __restrict__ W,
    const float* __restrict__ b, u16* __restrict__ hbf) {
  __shared__ float Ws[24 * HID];
  __shared__ float xin[16][24];
  int tid = threadIdx.x;
  int tc = blockIdx.y;
  for (int i = tid; i < 24 * HID; i += 256) Ws[i] = W[i];
  int n0 = blockIdx.x * 16;
  for (int i = tid; i < 16 * 24; i += 256) {
    int r = i / 24, c = i % 24;
    int n = n0 + r;
    xin[r][c] = (c < SDIM) ? xs[(size_t)n * SDIM + c]
                           : xdt[(size_t)tc * NN * DDIM + (size_t)n * DDIM + (c - SDIM)];
  }
  __syncthreads();
  int ch = tid & 127, rb = (tid >> 7) * 8;
  for (int r = rb; r < rb + 8; r++) {
    float acc = b[ch];
    #pragma unroll
    for (int k = 0; k < 24; k++) acc = fmaf(xin[r][k], Ws[k * HID + ch], acc);
    hbf[((size_t)tc * NN + n0 + r) * HID + ch] = f2bf(acc);
  }
}

#define TBM 128
#define TBN 64
#define TBK 64

// ---------------- GAT GEMM + fused attention-logit epilogue ----------------
__global__ __launch_bounds__(256) void k_bgemm_gat(const u16* __restrict__ A,
    const u16* __restrict__ Bt, const float* __restrict__ as_,
    const float* __restrict__ ad_, u16* __restrict__ xpbf,
    float* __restrict__ asrc, float* __restrict__ adst, int M) {
  __shared__ u16 As[TBM][TBK + 8];
  __shared__ u16 Bs[TBN][TBK + 8];
  int tid = threadIdx.x;
  int wid = tid >> 6, lane = tid & 63;
  int wr = wid >> 1, wc = wid & 1;
  int lrow = lane & 15, lgrp = lane >> 4;
  int row0 = blockIdx.x * TBM, col0 = blockIdx.y * TBN;
  floatx4 acc[4][2] = {};
  for (int k0 = 0; k0 < 128; k0 += TBK) {
    #pragma unroll
    for (int i = 0; i < 4; i++) {
      int idx = tid + i * 256;
      int r = idx >> 3, g = idx & 7;
      int gr = row0 + r;
      short8 v = {};
      if (gr < M) v = *(const short8*)(A + (size_t)gr * 128 + k0 + g * 8);
      *(short8*)&As[r][g * 8] = v;
    }
    #pragma unroll
    for (int i = 0; i < 2; i++) {
      int idx = tid + i * 256;
      int r = idx >> 3, g = idx & 7;
      *(short8*)&Bs[r][g * 8] = *(const short8*)(Bt + (size_t)(col0 + r) * 128 + k0 + g * 8);
    }
    __syncthreads();
    #pragma unroll
    for (int kk = 0; kk < TBK; kk += 32) {
      short8 bfr[2];
      #pragma unroll
      for (int n = 0; n < 2; n++)
        bfr[n] = *(const short8*)&Bs[wc * 32 + n * 16 + lrow][kk + lgrp * 8];
      #pragma unroll
      for (int m = 0; m < 4; m++) {
        short8 af = *(const short8*)&As[wr * 64 + m * 16 + lrow][kk + lgrp * 8];
        acc[m][0] = __builtin_amdgcn_mfma_f32_16x16x32_bf16(af, bfr[0], acc[m][0], 0, 0, 0);
        acc[m][1] = __builtin_amdgcn_mfma_f32_16x16x32_bf16(af, bfr[1], acc[m][1], 0, 0, 0);
      }
    }
    __syncthreads();
  }
  int head = (col0 >> 5) + wc;
  float as0 = as_[head * 32 + lrow], as1 = as_[head * 32 + 16 + lrow];
  float ad0 = ad_[head * 32 + lrow], ad1 = ad_[head * 32 + 16 + lrow];
  #pragma unroll
  for (int m = 0; m < 4; m++) {
    #pragma unroll
    for (int r = 0; r < 4; r++) {
      int grow = row0 + wr * 64 + m * 16 + lgrp * 4 + r;
      float v0 = acc[m][0][r], v1 = acc[m][1][r];
      if (grow < M) {
        xpbf[(size_t)grow * HID + col0 + wc * 32 + lrow]      = f2bf(v0);
        xpbf[(size_t)grow * HID + col0 + wc * 32 + 16 + lrow] = f2bf(v1);
      }
      float ps = v0 * as0 + v1 * as1;
      float pd = v0 * ad0 + v1 * ad1;
      #pragma unroll
      for (int off = 1; off < 16; off <<= 1) {
        ps += __shfl_xor(ps, off);
        pd += __shfl_xor(pd, off);
      }
      if (lrow == 0 && grow < M) {
        asrc[grow * HEADS + head] = ps;
        adst[grow * HEADS + head] = pd;
      }
    }
  }
}

// ---------------- edge-weight precompute: w[tc][j][h] = exp(leaky(asrc[src]+adst[dst])) ----
__global__ __launch_bounds__(256) void k_edgew(const int* __restrict__ col,
    const int* __restrict__ row, const float* __restrict__ asrc,
    const float* __restrict__ adst, float* __restrict__ wbuf) {
  int idx = blockIdx.x * 256 + threadIdx.x;       // TC*NE*HEADS exactly
  int h = idx & 3;
  int je = idx >> 2;                              // tc*NE + j
  int tc = je / NE;
  int j = je - tc * NE;
  int base = tc * NN;
  float ev = asrc[(size_t)(base + col[j]) * HEADS + h]
           + adst[(size_t)(base + row[j]) * HEADS + h];
  ev = (ev > 0.f) ? ev : 0.2f * ev;
  wbuf[idx] = __expf(fminf(ev, 80.f));
}

// ---------------- GAT aggregation + residual + LayerNorm + ReLU (TC-batched) ----------------
// weights precomputed; loop = load w + gather + fma only (4 independent acc sets).
__global__ __launch_bounds__(256) void k_aggr(const u16* __restrict__ xpbf,
    u16* __restrict__ hbf, const float* __restrict__ asrc,
    const float* __restrict__ adst, const float* __restrict__ wbuf,
    const int* __restrict__ rowptr, const int* __restrict__ col,
    const float* __restrict__ bias, const float* __restrict__ lng,
    const float* __restrict__ lnb) {
  int wid = threadIdx.x >> 6, lane = threadIdx.x & 63;
  int n = blockIdx.x * 4 + wid;                    // 0 .. TC*NN
  int tc = n / NN;
  int node = n - tc * NN, base = tc * NN;
  int hh = lane >> 4;
  float ad = adst[n * HEADS + hh];
  float e0 = asrc[n * HEADS + hh] + ad;            // self-loop
  e0 = (e0 > 0.f) ? e0 : 0.2f * e0;
  float w0 = __expf(fminf(e0, 80.f));
  u32 xv = ((const u32*)(xpbf + (size_t)n * HID))[lane];
  float den0 = w0, den1 = 0.f, den2 = 0.f, den3 = 0.f;
  float p00 = w0 * bf2f((u16)(xv & 0xffff)), p10 = 0.f, p20 = 0.f, p30 = 0.f;
  float p01 = w0 * bf2f((u16)(xv >> 16)),    p11 = 0.f, p21 = 0.f, p31 = 0.f;
  const float* wrow = wbuf + (size_t)tc * NE * HEADS;
  int rs = rowptr[node], re = rowptr[node + 1];
  int j = rs;
  for (; j + 4 <= re; j += 4) {                    // independent 4-edge unroll
    float w0e = wrow[(size_t)(j + 0) * HEADS + hh];
    float w1e = wrow[(size_t)(j + 1) * HEADS + hh];
    float w2e = wrow[(size_t)(j + 2) * HEADS + hh];
    float w3e = wrow[(size_t)(j + 3) * HEADS + hh];
    int s0 = base + col[j],     s1 = base + col[j + 1];
    int s2 = base + col[j + 2], s3 = base + col[j + 3];
    u32 x0 = ((const u32*)(xpbf + (size_t)s0 * HID))[lane];
    u32 x1 = ((const u32*)(xpbf + (size_t)s1 * HID))[lane];
    u32 x2 = ((const u32*)(xpbf + (size_t)s2 * HID))[lane];
    u32 x3 = ((const u32*)(xpbf + (size_t)s3 * HID))[lane];
    den0 += w0e; den1 += w1e; den2 += w2e; den3 += w3e;
    p00 = fmaf(w0e, bf2f((u16)(x0 & 0xffff)), p00);
    p10 = fmaf(w1e, bf2f((u16)(x1 & 0xffff)), p10);
    p20 = fmaf(w2e, bf2f((u16)(x2 & 0xffff)), p20);
    p30 = fmaf(w3e, bf2f((u16)(x3 & 0xffff)), p30);
    p01 = fmaf(w0e, bf2f((u16)(x0 >> 16)), p01);
    p11 = fmaf(w1e, bf2f((u16)(x1 >> 16)), p11);
    p21 = fmaf(w2e, bf2f((u16)(x2 >> 16)), p21);
    p31 = fmaf(w3e, bf2f((u16)(x3 >> 16)), p31);
  }
  for (; j < re; j++) {
    float w = wrow[(size_t)j * HEADS + hh];
    int s0 = base + col[j];
    u32 x0 = ((const u32*)(xpbf + (size_t)s0 * HID))[lane];
    den0 += w;
    p00 = fmaf(w, bf2f((u16)(x0 & 0xffff)), p00);
    p01 = fmaf(w, bf2f((u16)(x0 >> 16)), p01);
  }
  float den = (den0 + den1) + (den2 + den3);
  float mg0 = (p00 + p10) + (p20 + p30);
  float mg1 = (p01 + p11) + (p21 + p31);
  float inv = 1.f / (den + 1e-16f);
  int c0 = lane * 2;
  size_t hoff = (size_t)n * HID + c0;
  u32 hv = *(const u32*)(hbf + hoff);              // bf16 residual
  float o0 = mg0 * inv + bias[c0]     + bf2f((u16)(hv & 0xffff));
  float o1 = mg1 * inv + bias[c0 + 1] + bf2f((u16)(hv >> 16));
  float s2 = o0 + o1;
  #pragma unroll
  for (int off = 32; off; off >>= 1) s2 += __shfl_xor(s2, off);
  float mu = s2 * (1.f / HID);
  float d0 = o0 - mu, d1 = o1 - mu;
  float v2 = d0 * d0 + d1 * d1;
  #pragma unroll
  for (int off = 32; off; off >>= 1) v2 += __shfl_xor(v2, off);
  float rstd = rsqrtf(v2 * (1.f / HID) + 1e-5f);
  o0 = lng[c0] * d0 * rstd + lnb[c0];
  o1 = lng[c0 + 1] * d1 * rstd + lnb[c0 + 1];
  o0 = fmaxf(o0, 0.f);
  o1 = fmaxf(o1, 0.f);
  *(u32*)(hbf + hoff) = (u32)f2bf(o0) | ((u32)f2bf(o1) << 16);
}

// ---------------- LSTM GEMM + fused gate epilogue (shared body) ----------------
__device__ __forceinline__ void lstm_body(const u16* __restrict__ A0,
    const u16* __restrict__ A1, const u16* __restrict__ Bt,
    const float* __restrict__ bs, float* __restrict__ cst,
    u16* __restrict__ hout, char* smem, int bx, int by) {
  u16 (*As)[TBK + 8] = (u16(*)[TBK + 8])smem;
  u16 (*Bs)[TBK + 8] = (u16(*)[TBK + 8])(smem + TBM * (TBK + 8) * 2);
  float (*zs)[68] = (float(*)[68])smem;
  int tid = threadIdx.x;
  int wid = tid >> 6, lane = tid & 63;
  int wr = wid >> 1, wc = wid & 1;
  int lrow = lane & 15, lgrp = lane >> 4;
  int row0 = bx * TBM, col0 = by * TBN;
  floatx4 acc[4][2] = {};
  for (int k0 = 0; k0 < 256; k0 += TBK) {
    const u16* Ap = (k0 < 128) ? A0 : A1;
    int kb = k0 & 127;
    #pragma unroll
    for (int i = 0; i < 4; i++) {
      int idx = tid + i * 256;
      int r = idx >> 3, g = idx & 7;
      int gr = row0 + r;
      short8 v = {};
      if (gr < NN) v = *(const short8*)(Ap + (size_t)gr * 128 + kb + g * 8);
      *(short8*)&As[r][g * 8] = v;
    }
    #pragma unroll
    for (int i = 0; i < 2; i++) {
      int idx = tid + i * 256;
      int r = idx >> 3, g = idx & 7;
      *(short8*)&Bs[r][g * 8] = *(const short8*)(Bt + (size_t)(col0 + r) * 256 + k0 + g * 8);
    }
    __syncthreads();
    #pragma unroll
    for (int kk = 0; kk < TBK; kk += 32) {
      short8 bfr[2];
      #pragma unroll
      for (int n = 0; n < 2; n++)
        bfr[n] = *(const short8*)&Bs[wc * 32 + n * 16 + lrow][kk + lgrp * 8];
      #pragma unroll
      for (int m = 0; m < 4; m++) {
        short8 af = *(const short8*)&As[wr * 64 + m * 16 + lrow][kk + lgrp * 8];
        acc[m][0] = __builtin_amdgcn_mfma_f32_16x16x32_bf16(af, bfr[0], acc[m][0], 0, 0, 0);
        acc[m][1] = __builtin_amdgcn_mfma_f32_16x16x32_bf16(af, bfr[1], acc[m][1], 0, 0, 0);
      }
    }
    __syncthreads();
  }
  #pragma unroll
  for (int m = 0; m < 4; m++)
    #pragma unroll
    for (int n = 0; n < 2; n++)
      #pragma unroll
      for (int r = 0; r < 4; r++)
        zs[wr * 64 + m * 16 + lgrp * 4 + r][wc * 32 + n * 16 + lrow] = acc[m][n][r];
  __syncthreads();
  int ch0 = by * 16;
  #pragma unroll
  for (int it = 0; it < 8; it++) {
    int o = tid + it * 256;
    int r = o >> 4, lc = o & 15;
    int grow = row0 + r;
    if (grow < NN) {
      float4 zi = *(float4*)&zs[r][lc * 4];
      int ch = ch0 + lc;
      size_t gi = (size_t)grow * HID + ch;
      float ii = zi.x + bs[4 * ch + 0];
      float ff = zi.y + bs[4 * ch + 1];
      float gg = zi.z + bs[4 * ch + 2];
      float oo = zi.w + bs[4 * ch + 3];
      float si = 1.f / (1.f + __expf(-ii));
      float sf = 1.f / (1.f + __expf(-ff));
      float so = 1.f / (1.f + __expf(-oo));
      float tg = tanhf(gg);
      float cn = sf * cst[gi] + si * tg;
      cst[gi] = cn;
      hout[gi] = f2bf(so * tanhf(cn));
    }
  }
}

__global__ __launch_bounds__(256) void k_lstm1(const u16* __restrict__ A0,
    const u16* __restrict__ A1, const u16* __restrict__ Bt,
    const float* __restrict__ bs, float* __restrict__ cst, u16* __restrict__ hout) {
  __shared__ __align__(16) char smem[34816];
  lstm_body(A0, A1, Bt, bs, cst, hout, smem, blockIdx.x, blockIdx.y);
}

// merged: z==0 -> cell1(t), z==1 -> cell0(t+1) — independent jobs
__global__ __launch_bounds__(256) void k_lstm2(
    const u16* __restrict__ A0a, const u16* __restrict__ A1a, const u16* __restrict__ Bta,
    const float* __restrict__ bsa, float* __restrict__ csta, u16* __restrict__ houta,
    const u16* __restrict__ A0b, const u16* __restrict__ A1b, const u16* __restrict__ Btb,
    const float* __restrict__ bsb, float* __restrict__ cstb, u16* __restrict__ houtb) {
  __shared__ __align__(16) char smem[34816];
  if (blockIdx.z == 0) lstm_body(A0a, A1a, Bta, bsa, csta, houta, smem, blockIdx.x, blockIdx.y);
  else                 lstm_body(A0b, A1b, Btb, bsb, cstb, houtb, smem, blockIdx.x, blockIdx.y);
}

// ---------------- output MLP: relu(h1@W1+b1)@W2+b2 ----------------
__global__ __launch_bounds__(64) void k_mlp(const u16* __restrict__ h1,
    const float* __restrict__ W1, const float* __restrict__ b1,
    const float* __restrict__ W2, const float* __restrict__ b2,
    float* __restrict__ out) {
  int n = blockIdx.x, j = threadIdx.x;
  const u16* hr = h1 + (size_t)n * HID;
  float acc = b1[j];
  #pragma unroll 8
  for (int k = 0; k < HID; k++) acc = fmaf(bf2f(hr[k]), W1[(size_t)k * 64 + j], acc);
  acc = fmaxf(acc, 0.f);
  float p = acc * W2[j];
  #pragma unroll
  for (int off = 32; off; off >>= 1) p += __shfl_xor(p, off);
  if (j == 0) out[n] = p + b2[0];
}

extern "C" void kernel_launch(void* const* d_in, const int* in_sizes, int n_in,
                              void* d_out, int out_size, void* d_ws, size_t ws_size,
                              hipStream_t stream) {
  const float* xs    = (const float*)d_in[0];
  const float* xd    = (const float*)d_in[1];
  const int*   ei    = (const int*)d_in[2];
  const float* projW = (const float*)d_in[3];
  const float* projb = (const float*)d_in[4];
  const float* gatW  = (const float*)d_in[5];
  const float* attS  = (const float*)d_in[6];
  const float* attD  = (const float*)d_in[7];
  const float* gatb  = (const float*)d_in[8];
  const float* lng   = (const float*)d_in[9];
  const float* lnb   = (const float*)d_in[10];
  const float* Wih0  = (const float*)d_in[11];
  const float* Whh0  = (const float*)d_in[12];
  const float* bih0  = (const float*)d_in[13];
  const float* bhh0  = (const float*)d_in[14];
  const float* Wih1  = (const float*)d_in[15];
  const float* Whh1  = (const float*)d_in[16];
  const float* bih1  = (const float*)d_in[17];
  const float* bhh1  = (const float*)d_in[18];
  const float* oW1   = (const float*)d_in[19];
  const float* ob1   = (const float*)d_in[20];
  const float* oW2   = (const float*)d_in[21];
  const float* ob2   = (const float*)d_in[22];
  float* out = (float*)d_out;

  // -------- workspace layout (~97 MB) --------
  char* w = (char*)d_ws;
  size_t off = 0;
  auto alloc = [&](size_t bytes) { void* p = w + off; off += (bytes + 255) & ~(size_t)255; return p; };
  u16*   hbf   = (u16*)  alloc((size_t)TC * NN * HID * 2);   // bf16 h (GEMM A + residual)
  u16*   xpbf  = (u16*)  alloc((size_t)TC * NN * HID * 2);   // bf16 xp
  float* asrc  = (float*)alloc((size_t)TC * NN * HEADS * 4);
  float* adst  = (float*)alloc((size_t)TC * NN * HEADS * 4);
  float* wbuf  = (float*)alloc((size_t)TC * NE * HEADS * 4); // 20.5 MB edge weights
  float* c01   = (float*)alloc((size_t)2 * NN * HID * 4);    // c0,c1
  float* c0 = c01, *c1 = c01 + (size_t)NN * HID;
  u16*   h0p   = (u16*)  alloc((size_t)2 * NN * HID * 2);    // h0 ping-pong
  u16*   h1p   = (u16*)  alloc((size_t)2 * NN * HID * 2);    // h1 ping-pong
  u16*   h0buf[2] = { h0p, h0p + (size_t)NN * HID };
  u16*   h1buf[2] = { h1p, h1p + (size_t)NN * HID };
  u16*   Wc0bf = (u16*)alloc((size_t)512 * 256 * 2);
  u16*   Wc1bf = (u16*)alloc((size_t)512 * 256 * 2);
  float* bs01  = (float*)alloc((size_t)1024 * 4);
  float* bs0 = bs01, *bs1 = bs01 + 512;
  u16*   gatWbf= (u16*)alloc((size_t)NL * 128 * 128 * 2);
  int* cnt    = (int*)alloc((size_t)NN * 4);
  int* rowptr = (int*)alloc((size_t)(NN + 1) * 4);
  int* cursor = (int*)alloc((size_t)NN * 4);
  int* col    = (int*)alloc((size_t)NE * 4);
  int* rowi   = (int*)alloc((size_t)NE * 4);

  const int* esrc = ei;
  const int* edst = ei + NE;

  // -------- CSR (edge_index identical across t and layers) --------
  hipMemsetAsync(cnt, 0, (size_t)NN * 4, stream);
  k_count<<<(NE + 255) / 256, 256, 0, stream>>>(edst, cnt);
  k_scan<<<1, 1024, 0, stream>>>(cnt, rowptr, cursor);
  k_fill<<<(NE + 255) / 256, 256, 0, stream>>>(esrc, edst, cursor, col, rowi);

  // -------- weight/bias prep + state init --------
  k_prepw_lstm<<<(512 * 256) / 256, 256, 0, stream>>>(Wih0, Whh0, Wc0bf);
  k_prepw_lstm<<<(512 * 256) / 256, 256, 0, stream>>>(Wih1, Whh1, Wc1bf);
  k_prepb<<<2, 512, 0, stream>>>(bih0, bhh0, bih1, bhh1, bs01);
  k_prepw_gat<<<(NL * 128 * 128) / 256, 256, 0, stream>>>(gatW, gatWbf);
  hipMemsetAsync(c01, 0, (size_t)2 * NN * HID * 4, stream);
  hipMemsetAsync(h0buf[0], 0, (size_t)NN * HID * 2, stream);
  hipMemsetAsync(h1buf[0], 0, (size_t)NN * HID * 2, stream);

  const int gx  = (NN + TBM - 1) / TBM;             // 157
  const int gx2 = (TC * NN + TBM - 1) / TBM;        // 625

  auto gnn_chunk = [&](int tcb) {
    k_proj<<<dim3(NN / 16, TC), 256, 0, stream>>>(
        xs, xd + (size_t)(tcb * TC) * NN * DDIM, projW, projb, hbf);
    for (int l = 0; l < NL; l++) {
      k_bgemm_gat<<<dim3(gx2, 2), 256, 0, stream>>>(
          hbf, gatWbf + (size_t)l * 128 * 128,
          attS + l * HEADS * DPH, attD + l * HEADS * DPH,
          xpbf, asrc, adst, TC * NN);
      k_edgew<<<(TC * NE * HEADS) / 256, 256, 0, stream>>>(col, rowi, asrc, adst, wbuf);
      k_aggr<<<TC * NN / 4, 256, 0, stream>>>(
          xpbf, hbf, asrc, adst, wbuf, rowptr, col, gatb + (size_t)l * HID,
          lng + (size_t)l * HID, lnb + (size_t)l * HID);
    }
  };
  // merged LSTM step: cell1(t) + cell0(t+1)  [independent; buffer audit in journal]
  auto lstm_merged = [&](int t) {
    int pi = t & 1;
    int s1 = (t + 1) & (TC - 1);                   // hbf slot of t+1 within its chunk
    k_lstm2<<<dim3(gx, 8, 2), 256, 0, stream>>>(
        h0buf[pi ^ 1], h1buf[pi], Wc1bf, bs1, c1, h1buf[pi ^ 1],
        hbf + (size_t)s1 * NN * HID, h0buf[pi ^ 1], Wc0bf, bs0, c0, h0buf[pi]);
  };

  // -------- pipeline: GNN chunks + dependency-merged LSTM chain --------
  gnn_chunk(0);
  k_lstm1<<<dim3(gx, 8), 256, 0, stream>>>(hbf, h0buf[0], Wc0bf, bs0, c0, h0buf[1]);  // cell0(t=0)
  lstm_merged(0); lstm_merged(1); lstm_merged(2);
  for (int tcb = 1; tcb < TT / TC; tcb++) {
    gnn_chunk(tcb);
    lstm_merged(4 * tcb - 1);
    lstm_merged(4 * tcb);
    lstm_merged(4 * tcb + 1);
    if (tcb < TT / TC - 1) lstm_merged(4 * tcb + 2);
    else {
      lstm_merged(4 * tcb + 2);                    // t=22
      // final cell1(t=23): reads h0buf[0], h1buf[1] -> h1buf[0]
      k_lstm1<<<dim3(gx, 8), 256, 0, stream>>>(h0buf[0], h1buf[1], Wc1bf, bs1, c1, h1buf[0]);
    }
  }

  // TT even -> final h1 lives in h1buf[0]
  k_mlp<<<NN, 64, 0, stream>>>(h1buf[0], oW1, ob1, oW2, ob2, out);
}

// Round 13
// 3301.268 us; speedup vs baseline: 1.2215x; 1.0051x over previous
//
#include <hip/hip_runtime.h>
#include <hip/hip_bf16.h>
#include <math.h>

#define NN   20000
#define NE   320000
#define TT   24
#define SDIM 16
#define DDIM 8
#define HID  128
#define HEADS 4
#define DPH  32
#define NL   3
#define TC   4          // timesteps batched per GNN chunk (divides TT)

typedef unsigned short u16;
typedef unsigned int   u32;
typedef unsigned long long u64;
typedef __attribute__((ext_vector_type(8))) short  short8;
typedef __attribute__((ext_vector_type(4))) float  floatx4;

__device__ __forceinline__ u16 f2bf(float x) {          // round-to-nearest-even
  u32 u = __float_as_uint(x);
  return (u16)((u + 0x7fff + ((u >> 16) & 1)) >> 16);
}
__device__ __forceinline__ float bf2f(u16 b) {
  return __uint_as_float(((u32)b) << 16);
}

// ---------------- CSR build (group edges by dst) ----------------
__global__ void k_count(const int* __restrict__ dst, int* __restrict__ cnt) {
  int e = blockIdx.x * 256 + threadIdx.x;
  if (e < NE) atomicAdd(&cnt[dst[e]], 1);
}

__global__ __launch_bounds__(1024) void k_scan(const int* __restrict__ cnt,
    int* __restrict__ rowptr, int* __restrict__ cursor) {
  __shared__ int sh[1024];
  int tid = threadIdx.x;
  const int CH = 20;                      // 1024*20 >= NN
  int base = tid * CH;
  int local[CH];
  int s = 0;
  #pragma unroll
  for (int i = 0; i < CH; i++) {
    int idx = base + i;
    int v = (idx < NN) ? cnt[idx] : 0;
    local[i] = s;
    s += v;
  }
  sh[tid] = s;
  __syncthreads();
  for (int off = 1; off < 1024; off <<= 1) {
    int tv = (tid >= off) ? sh[tid - off] : 0;
    __syncthreads();
    sh[tid] += tv;
    __syncthreads();
  }
  int pre = (tid > 0) ? sh[tid - 1] : 0;
  #pragma unroll
  for (int i = 0; i < CH; i++) {
    int idx = base + i;
    if (idx < NN) { int e = pre + local[i]; rowptr[idx] = e; cursor[idx] = e; }
  }
  if (tid == 1023) rowptr[NN] = sh[1023];
}

__global__ void k_fill(const int* __restrict__ src, const int* __restrict__ dst,
    int* __restrict__ cursor, int* __restrict__ col, int* __restrict__ row) {
  int e = blockIdx.x * 256 + threadIdx.x;
  if (e < NE) {
    int d = dst[e];
    int pos = atomicAdd(&cursor[d], 1);
    col[pos] = src[e];
    row[pos] = d;
  }
}

// ---------------- weight prep ----------------
// LSTM weights, GATE-INTERLEAVED: Bt[4c+g][k] = W[g*128+c][k], W = [Wih | Whh]
__global__ void k_prepw_lstm(const float* __restrict__ Wih, const float* __restrict__ Whh,
    u16* __restrict__ Bt) {
  int idx = blockIdx.x * 256 + threadIdx.x;
  if (idx < 512 * 256) {
    int jp = idx >> 8, k = idx & 255;
    int c = jp >> 2, g = jp & 3;
    int j = g * 128 + c;
    float v = (k < 128) ? Wih[(size_t)j * 128 + k] : Whh[(size_t)j * 128 + (k - 128)];
    Bt[idx] = f2bf(v);
  }
}
// combined bias, gate-interleaved: bs[4c+g] = bih[g*128+c] + bhh[g*128+c]; 2 cells
__global__ void k_prepb(const float* __restrict__ bih0, const float* __restrict__ bhh0,
    const float* __restrict__ bih1, const float* __restrict__ bhh1,
    float* __restrict__ bs01) {
  int t = threadIdx.x;               // 512 per block, blockIdx.x = cell
  const float* bih = blockIdx.x ? bih1 : bih0;
  const float* bhh = blockIdx.x ? bhh1 : bhh0;
  int c = t >> 2, g = t & 3;
  bs01[blockIdx.x * 512 + t] = bih[g * 128 + c] + bhh[g * 128 + c];
}
// GAT: Btg[l][n][k] = gatW[l][k][n]
__global__ void k_prepw_gat(const float* __restrict__ gatW, u16* __restrict__ Btg) {
  int idx = blockIdx.x * 256 + threadIdx.x;
  if (idx < NL * 128 * 128) {
    int l = idx >> 14, r = idx & 16383;
    int n = r >> 7, k = r & 127;
    Btg[idx] = f2bf(gatW[(size_t)l * 16384 + k * 128 + n]);
  }
}

// ---------------- input projection (TC timesteps) ----------------
__global__ __launch_bounds__(256) void k_proj(const float* __restrict__ xs,
    const float* __restrict__ xdt, const float* __restrict__ W,
    const float* __restrict__ b, u16* __restrict__ hbf) {
  __shared__ float Ws[24 * HID];
  __shared__ float xin[16][24];
  int tid = threadIdx.x;
  int tc = blockIdx.y;
  for (int i = tid; i < 24 * HID; i += 256) Ws[i] = W[i];
  int n0 = blockIdx.x * 16;
  for (int i = tid; i < 16 * 24; i += 256) {
    int r = i / 24, c = i % 24;
    int n = n0 + r;
    xin[r][c] = (c < SDIM) ? xs[(size_t)n * SDIM + c]
                           : xdt[(size_t)tc * NN * DDIM + (size_t)n * DDIM + (c - SDIM)];
  }
  __syncthreads();
  int ch = tid & 127, rb = (tid >> 7) * 8;
  for (int r = rb; r < rb + 8; r++) {
    float acc = b[ch];
    #pragma unroll
    for (int k = 0; k < 24; k++) acc = fmaf(xin[r][k], Ws[k * HID + ch], acc);
    hbf[((size_t)tc * NN + n0 + r) * HID + ch] = f2bf(acc);
  }
}

#define TBM 128
#define TBN 64
#define TBK 64

// ---------------- GAT GEMM + fused attention-logit epilogue ----------------
__global__ __launch_bounds__(256) void k_bgemm_gat(const u16* __restrict__ A,
    const u16* __restrict__ Bt, const float* __restrict__ as_,
    const float* __restrict__ ad_, u16* __restrict__ xpbf,
    float* __restrict__ asrc, float* __restrict__ adst, int M) {
  __shared__ u16 As[TBM][TBK + 8];
  __shared__ u16 Bs[TBN][TBK + 8];
  int tid = threadIdx.x;
  int wid = tid >> 6, lane = tid & 63;
  int wr = wid >> 1, wc = wid & 1;
  int lrow = lane & 15, lgrp = lane >> 4;
  int row0 = blockIdx.x * TBM, col0 = blockIdx.y * TBN;
  floatx4 acc[4][2] = {};
  for (int k0 = 0; k0 < 128; k0 += TBK) {
    #pragma unroll
    for (int i = 0; i < 4; i++) {
      int idx = tid + i * 256;
      int r = idx >> 3, g = idx & 7;
      int gr = row0 + r;
      short8 v = {};
      if (gr < M) v = *(const short8*)(A + (size_t)gr * 128 + k0 + g * 8);
      *(short8*)&As[r][g * 8] = v;
    }
    #pragma unroll
    for (int i = 0; i < 2; i++) {
      int idx = tid + i * 256;
      int r = idx >> 3, g = idx & 7;
      *(short8*)&Bs[r][g * 8] = *(const short8*)(Bt + (size_t)(col0 + r) * 128 + k0 + g * 8);
    }
    __syncthreads();
    #pragma unroll
    for (int kk = 0; kk < TBK; kk += 32) {
      short8 bfr[2];
      #pragma unroll
      for (int n = 0; n < 2; n++)
        bfr[n] = *(const short8*)&Bs[wc * 32 + n * 16 + lrow][kk + lgrp * 8];
      #pragma unroll
      for (int m = 0; m < 4; m++) {
        short8 af = *(const short8*)&As[wr * 64 + m * 16 + lrow][kk + lgrp * 8];
        acc[m][0] = __builtin_amdgcn_mfma_f32_16x16x32_bf16(af, bfr[0], acc[m][0], 0, 0, 0);
        acc[m][1] = __builtin_amdgcn_mfma_f32_16x16x32_bf16(af, bfr[1], acc[m][1], 0, 0, 0);
      }
    }
    __syncthreads();
  }
  int head = (col0 >> 5) + wc;
  float as0 = as_[head * 32 + lrow], as1 = as_[head * 32 + 16 + lrow];
  float ad0 = ad_[head * 32 + lrow], ad1 = ad_[head * 32 + 16 + lrow];
  #pragma unroll
  for (int m = 0; m < 4; m++) {
    #pragma unroll
    for (int r = 0; r < 4; r++) {
      int grow = row0 + wr * 64 + m * 16 + lgrp * 4 + r;
      float v0 = acc[m][0][r], v1 = acc[m][1][r];
      if (grow < M) {
        xpbf[(size_t)grow * HID + col0 + wc * 32 + lrow]      = f2bf(v0);
        xpbf[(size_t)grow * HID + col0 + wc * 32 + 16 + lrow] = f2bf(v1);
      }
      float ps = v0 * as0 + v1 * as1;
      float pd = v0 * ad0 + v1 * ad1;
      #pragma unroll
      for (int off = 1; off < 16; off <<= 1) {
        ps += __shfl_xor(ps, off);
        pd += __shfl_xor(pd, off);
      }
      if (lrow == 0 && grow < M) {
        asrc[grow * HEADS + head] = ps;
        adst[grow * HEADS + head] = pd;
      }
    }
  }
}

// ---------------- edge-weight precompute: ewp[tc][j] = bf16x4 (4 heads) packed u64 ----
// one thread per (tc, edge): 2 coalesced float4 gathers, one 8B write.
__global__ __launch_bounds__(256) void k_edgew(const int* __restrict__ col,
    const int* __restrict__ row, const float* __restrict__ asrc,
    const float* __restrict__ adst, u64* __restrict__ ewp) {
  int idx = blockIdx.x * 256 + threadIdx.x;       // TC*NE exactly
  int tc = idx / NE;
  int j = idx - tc * NE;
  int base = tc * NN;
  float4 a = *(const float4*)(asrc + (size_t)(base + col[j]) * HEADS);
  float4 b = *(const float4*)(adst + (size_t)(base + row[j]) * HEADS);
  float e0 = a.x + b.x, e1 = a.y + b.y, e2 = a.z + b.z, e3 = a.w + b.w;
  e0 = (e0 > 0.f) ? e0 : 0.2f * e0;
  e1 = (e1 > 0.f) ? e1 : 0.2f * e1;
  e2 = (e2 > 0.f) ? e2 : 0.2f * e2;
  e3 = (e3 > 0.f) ? e3 : 0.2f * e3;
  u64 w = (u64)f2bf(__expf(fminf(e0, 80.f)))
        | ((u64)f2bf(__expf(fminf(e1, 80.f))) << 16)
        | ((u64)f2bf(__expf(fminf(e2, 80.f))) << 32)
        | ((u64)f2bf(__expf(fminf(e3, 80.f))) << 48);
  ewp[idx] = w;
}

// ---------------- GAT aggregation + residual + LayerNorm + ReLU (TC-batched) ----------------
// packed bf16 edge weights: one wave-uniform u64 load per edge; loop = gather + fma.
__global__ __launch_bounds__(256) void k_aggr(const u16* __restrict__ xpbf,
    u16* __restrict__ hbf, const float* __restrict__ asrc,
    const float* __restrict__ adst, const u64* __restrict__ ewp,
    const int* __restrict__ rowptr, const int* __restrict__ col,
    const float* __restrict__ bias, const float* __restrict__ lng,
    const float* __restrict__ lnb) {
  int wid = threadIdx.x >> 6, lane = threadIdx.x & 63;
  int n = blockIdx.x * 4 + wid;                    // 0 .. TC*NN
  int tc = n / NN;
  int node = n - tc * NN, base = tc * NN;
  int hh = lane >> 4;
  int hsh = hh * 16;                               // shift for packed-w extract
  float ad = adst[n * HEADS + hh];
  float e0 = asrc[n * HEADS + hh] + ad;            // self-loop (fp32 weight)
  e0 = (e0 > 0.f) ? e0 : 0.2f * e0;
  float w0 = __expf(fminf(e0, 80.f));
  u32 xv = ((const u32*)(xpbf + (size_t)n * HID))[lane];
  int c0 = lane * 2;
  size_t hoff = (size_t)n * HID + c0;
  u32 hv = *(const u32*)(hbf + hoff);              // residual (load early, store later)
  float den0 = w0, den1 = 0.f, den2 = 0.f, den3 = 0.f;
  float p00 = w0 * bf2f((u16)(xv & 0xffff)), p10 = 0.f, p20 = 0.f, p30 = 0.f;
  float p01 = w0 * bf2f((u16)(xv >> 16)),    p11 = 0.f, p21 = 0.f, p31 = 0.f;
  const u64* ewrow = ewp + (size_t)tc * NE;
  int rs = rowptr[node], re = rowptr[node + 1];
  int j = rs;
  for (; j + 4 <= re; j += 4) {                    // independent 4-edge unroll
    u64 wp0 = ewrow[j + 0];
    u64 wp1 = ewrow[j + 1];
    u64 wp2 = ewrow[j + 2];
    u64 wp3 = ewrow[j + 3];
    int s0 = base + col[j],     s1 = base + col[j + 1];
    int s2 = base + col[j + 2], s3 = base + col[j + 3];
    u32 x0 = ((const u32*)(xpbf + (size_t)s0 * HID))[lane];
    u32 x1 = ((const u32*)(xpbf + (size_t)s1 * HID))[lane];
    u32 x2 = ((const u32*)(xpbf + (size_t)s2 * HID))[lane];
    u32 x3 = ((const u32*)(xpbf + (size_t)s3 * HID))[lane];
    float w0e = bf2f((u16)(wp0 >> hsh));
    float w1e = bf2f((u16)(wp1 >> hsh));
    float w2e = bf2f((u16)(wp2 >> hsh));
    float w3e = bf2f((u16)(wp3 >> hsh));
    den0 += w0e; den1 += w1e; den2 += w2e; den3 += w3e;
    p00 = fmaf(w0e, bf2f((u16)(x0 & 0xffff)), p00);
    p10 = fmaf(w1e, bf2f((u16)(x1 & 0xffff)), p10);
    p20 = fmaf(w2e, bf2f((u16)(x2 & 0xffff)), p20);
    p30 = fmaf(w3e, bf2f((u16)(x3 & 0xffff)), p30);
    p01 = fmaf(w0e, bf2f((u16)(x0 >> 16)), p01);
    p11 = fmaf(w1e, bf2f((u16)(x1 >> 16)), p11);
    p21 = fmaf(w2e, bf2f((u16)(x2 >> 16)), p21);
    p31 = fmaf(w3e, bf2f((u16)(x3 >> 16)), p31);
  }
  for (; j < re; j++) {
    u64 wp = ewrow[j];
    int s0 = base + col[j];
    u32 x0 = ((const u32*)(xpbf + (size_t)s0 * HID))[lane];
    float w = bf2f((u16)(wp >> hsh));
    den0 += w;
    p00 = fmaf(w, bf2f((u16)(x0 & 0xffff)), p00);
    p01 = fmaf(w, bf2f((u16)(x0 >> 16)), p01);
  }
  float den = (den0 + den1) + (den2 + den3);
  float mg0 = (p00 + p10) + (p20 + p30);
  float mg1 = (p01 + p11) + (p21 + p31);
  float inv = 1.f / (den + 1e-16f);
  float o0 = mg0 * inv + bias[c0]     + bf2f((u16)(hv & 0xffff));
  float o1 = mg1 * inv + bias[c0 + 1] + bf2f((u16)(hv >> 16));
  float s2 = o0 + o1;
  #pragma unroll
  for (int off = 32; off; off >>= 1) s2 += __shfl_xor(s2, off);
  float mu = s2 * (1.f / HID);
  float d0 = o0 - mu, d1 = o1 - mu;
  float v2 = d0 * d0 + d1 * d1;
  #pragma unroll
  for (int off = 32; off; off >>= 1) v2 += __shfl_xor(v2, off);
  float rstd = rsqrtf(v2 * (1.f / HID) + 1e-5f);
  o0 = lng[c0] * d0 * rstd + lnb[c0];
  o1 = lng[c0 + 1] * d1 * rstd + lnb[c0 + 1];
  o0 = fmaxf(o0, 0.f);
  o1 = fmaxf(o1, 0.f);
  *(u32*)(hbf + hoff) = (u32)f2bf(o0) | ((u32)f2bf(o1) << 16);
}

// ---------------- LSTM GEMM + fused gate epilogue (shared body) ----------------
__device__ __forceinline__ void lstm_body(const u16* __restrict__ A0,
    const u16* __restrict__ A1, const u16* __restrict__ Bt,
    const float* __restrict__ bs, float* __restrict__ cst,
    u16* __restrict__ hout, char* smem, int bx, int by) {
  u16 (*As)[TBK + 8] = (u16(*)[TBK + 8])smem;
  u16 (*Bs)[TBK + 8] = (u16(*)[TBK + 8])(smem + TBM * (TBK + 8) * 2);
  float (*zs)[68] = (float(*)[68])smem;
  int tid = threadIdx.x;
  int wid = tid >> 6, lane = tid & 63;
  int wr = wid >> 1, wc = wid & 1;
  int lrow = lane & 15, lgrp = lane >> 4;
  int row0 = bx * TBM, col0 = by * TBN;
  floatx4 acc[4][2] = {};
  for (int k0 = 0; k0 < 256; k0 += TBK) {
    const u16* Ap = (k0 < 128) ? A0 : A1;
    int kb = k0 & 127;
    #pragma unroll
    for (int i = 0; i < 4; i++) {
      int idx = tid + i * 256;
      int r = idx >> 3, g = idx & 7;
      int gr = row0 + r;
      short8 v = {};
      if (gr < NN) v = *(const short8*)(Ap + (size_t)gr * 128 + kb + g * 8);
      *(short8*)&As[r][g * 8] = v;
    }
    #pragma unroll
    for (int i = 0; i < 2; i++) {
      int idx = tid + i * 256;
      int r = idx >> 3, g = idx & 7;
      *(short8*)&Bs[r][g * 8] = *(const short8*)(Bt + (size_t)(col0 + r) * 256 + k0 + g * 8);
    }
    __syncthreads();
    #pragma unroll
    for (int kk = 0; kk < TBK; kk += 32) {
      short8 bfr[2];
      #pragma unroll
      for (int n = 0; n < 2; n++)
        bfr[n] = *(const short8*)&Bs[wc * 32 + n * 16 + lrow][kk + lgrp * 8];
      #pragma unroll
      for (int m = 0; m < 4; m++) {
        short8 af = *(const short8*)&As[wr * 64 + m * 16 + lrow][kk + lgrp * 8];
        acc[m][0] = __builtin_amdgcn_mfma_f32_16x16x32_bf16(af, bfr[0], acc[m][0], 0, 0, 0);
        acc[m][1] = __builtin_amdgcn_mfma_f32_16x16x32_bf16(af, bfr[1], acc[m][1], 0, 0, 0);
      }
    }
    __syncthreads();
  }
  #pragma unroll
  for (int m = 0; m < 4; m++)
    #pragma unroll
    for (int n = 0; n < 2; n++)
      #pragma unroll
      for (int r = 0; r < 4; r++)
        zs[wr * 64 + m * 16 + lgrp * 4 + r][wc * 32 + n * 16 + lrow] = acc[m][n][r];
  __syncthreads();
  int ch0 = by * 16;
  #pragma unroll
  for (int it = 0; it < 8; it++) {
    int o = tid + it * 256;
    int r = o >> 4, lc = o & 15;
    int grow = row0 + r;
    if (grow < NN) {
      float4 zi = *(float4*)&zs[r][lc * 4];
      int ch = ch0 + lc;
      size_t gi = (size_t)grow * HID + ch;
      float ii = zi.x + bs[4 * ch + 0];
      float ff = zi.y + bs[4 * ch + 1];
      float gg = zi.z + bs[4 * ch + 2];
      float oo = zi.w + bs[4 * ch + 3];
      float si = 1.f / (1.f + __expf(-ii));
      float sf = 1.f / (1.f + __expf(-ff));
      float so = 1.f / (1.f + __expf(-oo));
      float tg = tanhf(gg);
      float cn = sf * cst[gi] + si * tg;
      cst[gi] = cn;
      hout[gi] = f2bf(so * tanhf(cn));
    }
  }
}

__global__ __launch_bounds__(256) void k_lstm1(const u16* __restrict__ A0,
    const u16* __restrict__ A1, const u16* __restrict__ Bt,
    const float* __restrict__ bs, float* __restrict__ cst, u16* __restrict__ hout) {
  __shared__ __align__(16) char smem[34816];
  lstm_body(A0, A1, Bt, bs, cst, hout, smem, blockIdx.x, blockIdx.y);
}

// merged: z==0 -> cell1(t), z==1 -> cell0(t+1) — independent jobs
__global__ __launch_bounds__(256) void k_lstm2(
    const u16* __restrict__ A0a, const u16* __restrict__ A1a, const u16* __restrict__ Bta,
    const float* __restrict__ bsa, float* __restrict__ csta, u16* __restrict__ houta,
    const u16* __restrict__ A0b, const u16* __restrict__ A1b, const u16* __restrict__ Btb,
    const float* __restrict__ bsb, float* __restrict__ cstb, u16* __restrict__ houtb) {
  __shared__ __align__(16) char smem[34816];
  if (blockIdx.z == 0) lstm_body(A0a, A1a, Bta, bsa, csta, houta, smem, blockIdx.x, blockIdx.y);
  else                 lstm_body(A0b, A1b, Btb, bsb, cstb, houtb, smem, blockIdx.x, blockIdx.y);
}

// ---------------- output MLP: relu(h1@W1+b1)@W2+b2 ----------------
__global__ __launch_bounds__(64) void k_mlp(const u16* __restrict__ h1,
    const float* __restrict__ W1, const float* __restrict__ b1,
    const float* __restrict__ W2, const float* __restrict__ b2,
    float* __restrict__ out) {
  int n = blockIdx.x, j = threadIdx.x;
  const u16* hr = h1 + (size_t)n * HID;
  float acc = b1[j];
  #pragma unroll 8
  for (int k = 0; k < HID; k++) acc = fmaf(bf2f(hr[k]), W1[(size_t)k * 64 + j], acc);
  acc = fmaxf(acc, 0.f);
  float p = acc * W2[j];
  #pragma unroll
  for (int off = 32; off; off >>= 1) p += __shfl_xor(p, off);
  if (j == 0) out[n] = p + b2[0];
}

extern "C" void kernel_launch(void* const* d_in, const int* in_sizes, int n_in,
                              void* d_out, int out_size, void* d_ws, size_t ws_size,
                              hipStream_t stream) {
  const float* xs    = (const float*)d_in[0];
  const float* xd    = (const float*)d_in[1];
  const int*   ei    = (const int*)d_in[2];
  const float* projW = (const float*)d_in[3];
  const float* projb = (const float*)d_in[4];
  const float* gatW  = (const float*)d_in[5];
  const float* attS  = (const float*)d_in[6];
  const float* attD  = (const float*)d_in[7];
  const float* gatb  = (const float*)d_in[8];
  const float* lng   = (const float*)d_in[9];
  const float* lnb   = (const float*)d_in[10];
  const float* Wih0  = (const float*)d_in[11];
  const float* Whh0  = (const float*)d_in[12];
  const float* bih0  = (const float*)d_in[13];
  const float* bhh0  = (const float*)d_in[14];
  const float* Wih1  = (const float*)d_in[15];
  const float* Whh1  = (const float*)d_in[16];
  const float* bih1  = (const float*)d_in[17];
  const float* bhh1  = (const float*)d_in[18];
  const float* oW1   = (const float*)d_in[19];
  const float* ob1   = (const float*)d_in[20];
  const float* oW2   = (const float*)d_in[21];
  const float* ob2   = (const float*)d_in[22];
  float* out = (float*)d_out;

  // -------- workspace layout (~87 MB) --------
  char* w = (char*)d_ws;
  size_t off = 0;
  auto alloc = [&](size_t bytes) { void* p = w + off; off += (bytes + 255) & ~(size_t)255; return p; };
  u16*   hbf   = (u16*)  alloc((size_t)TC * NN * HID * 2);   // bf16 h (GEMM A + residual)
  u16*   xpbf  = (u16*)  alloc((size_t)TC * NN * HID * 2);   // bf16 xp
  float* asrc  = (float*)alloc((size_t)TC * NN * HEADS * 4);
  float* adst  = (float*)alloc((size_t)TC * NN * HEADS * 4);
  u64*   ewp   = (u64*)  alloc((size_t)TC * NE * 8);         // 10.2 MB packed bf16x4 weights
  float* c01   = (float*)alloc((size_t)2 * NN * HID * 4);    // c0,c1
  float* c0 = c01, *c1 = c01 + (size_t)NN * HID;
  u16*   h0p   = (u16*)  alloc((size_t)2 * NN * HID * 2);    // h0 ping-pong
  u16*   h1p   = (u16*)  alloc((size_t)2 * NN * HID * 2);    // h1 ping-pong
  u16*   h0buf[2] = { h0p, h0p + (size_t)NN * HID };
  u16*   h1buf[2] = { h1p, h1p + (size_t)NN * HID };
  u16*   Wc0bf = (u16*)alloc((size_t)512 * 256 * 2);
  u16*   Wc1bf = (u16*)alloc((size_t)512 * 256 * 2);
  float* bs01  = (float*)alloc((size_t)1024 * 4);
  float* bs0 = bs01, *bs1 = bs01 + 512;
  u16*   gatWbf= (u16*)alloc((size_t)NL * 128 * 128 * 2);
  int* cnt    = (int*)alloc((size_t)NN * 4);
  int* rowptr = (int*)alloc((size_t)(NN + 1) * 4);
  int* cursor = (int*)alloc((size_t)NN * 4);
  int* col    = (int*)alloc((size_t)NE * 4);
  int* rowi   = (int*)alloc((size_t)NE * 4);

  const int* esrc = ei;
  const int* edst = ei + NE;

  // -------- CSR (edge_index identical across t and layers) --------
  hipMemsetAsync(cnt, 0, (size_t)NN * 4, stream);
  k_count<<<(NE + 255) / 256, 256, 0, stream>>>(edst, cnt);
  k_scan<<<1, 1024, 0, stream>>>(cnt, rowptr, cursor);
  k_fill<<<(NE + 255) / 256, 256, 0, stream>>>(esrc, edst, cursor, col, rowi);

  // -------- weight/bias prep + state init --------
  k_prepw_lstm<<<(512 * 256) / 256, 256, 0, stream>>>(Wih0, Whh0, Wc0bf);
  k_prepw_lstm<<<(512 * 256) / 256, 256, 0, stream>>>(Wih1, Whh1, Wc1bf);
  k_prepb<<<2, 512, 0, stream>>>(bih0, bhh0, bih1, bhh1, bs01);
  k_prepw_gat<<<(NL * 128 * 128) / 256, 256, 0, stream>>>(gatW, gatWbf);
  hipMemsetAsync(c01, 0, (size_t)2 * NN * HID * 4, stream);
  hipMemsetAsync(h0buf[0], 0, (size_t)NN * HID * 2, stream);
  hipMemsetAsync(h1buf[0], 0, (size_t)NN * HID * 2, stream);

  const int gx  = (NN + TBM - 1) / TBM;             // 157
  const int gx2 = (TC * NN + TBM - 1) / TBM;        // 625

  auto gnn_chunk = [&](int tcb) {
    k_proj<<<dim3(NN / 16, TC), 256, 0, stream>>>(
        xs, xd + (size_t)(tcb * TC) * NN * DDIM, projW, projb, hbf);
    for (int l = 0; l < NL; l++) {
      k_bgemm_gat<<<dim3(gx2, 2), 256, 0, stream>>>(
          hbf, gatWbf + (size_t)l * 128 * 128,
          attS + l * HEADS * DPH, attD + l * HEADS * DPH,
          xpbf, asrc, adst, TC * NN);
      k_edgew<<<(TC * NE) / 256, 256, 0, stream>>>(col, rowi, asrc, adst, ewp);
      k_aggr<<<TC * NN / 4, 256, 0, stream>>>(
          xpbf, hbf, asrc, adst, ewp, rowptr, col, gatb + (size_t)l * HID,
          lng + (size_t)l * HID, lnb + (size_t)l * HID);
    }
  };
  // merged LSTM step: cell1(t) + cell0(t+1)  [independent; buffer audit in journal]
  auto lstm_merged = [&](int t) {
    int pi = t & 1;
    int s1 = (t + 1) & (TC - 1);                   // hbf slot of t+1 within its chunk
    k_lstm2<<<dim3(gx, 8, 2), 256, 0, stream>>>(
        h0buf[pi ^ 1], h1buf[pi], Wc1bf, bs1, c1, h1buf[pi ^ 1],
        hbf + (size_t)s1 * NN * HID, h0buf[pi ^ 1], Wc0bf, bs0, c0, h0buf[pi]);
  };

  // -------- pipeline: GNN chunks + dependency-merged LSTM chain --------
  gnn_chunk(0);
  k_lstm1<<<dim3(gx, 8), 256, 0, stream>>>(hbf, h0buf[0], Wc0bf, bs0, c0, h0buf[1]);  // cell0(t=0)
  lstm_merged(0); lstm_merged(1); lstm_merged(2);
  for (int tcb = 1; tcb < TT / TC; tcb++) {
    gnn_chunk(tcb);
    lstm_merged(4 * tcb - 1);
    lstm_merged(4 * tcb);
    lstm_merged(4 * tcb + 1);
    if (tcb < TT / TC - 1) lstm_merged(4 * tcb + 2);
    else {
      lstm_merged(4 * tcb + 2);                    // t=22
      // final cell1(t=23): reads h0buf[0], h1buf[1] -> h1buf[0]
      k_lstm1<<<dim3(gx, 8), 256, 0, stream>>>(h0buf[0], h1buf[1], Wc1bf, bs1, c1, h1buf[0]);
    }
  }

  // TT even -> final h1 lives in h1buf[0]
  k_mlp<<<NN, 64, 0, stream>>>(h1buf[0], oW1, ob1, oW2, ob2, out);
}

// Round 14
// 3143.927 us; speedup vs baseline: 1.2826x; 1.0500x over previous
//
#include <hip/hip_runtime.h>
#include <hip/hip_bf16.h>
#include <math.h>

#define NN   20000
#define NE   320000
#define TT   24
#define SDIM 16
#define DDIM 8
#define HID  128
#define HEADS 4
#define DPH  32
#define NL   3
#define TC   4          // timesteps batched per GNN chunk (divides TT)

typedef unsigned short u16;
typedef unsigned int   u32;
typedef unsigned long long u64;
typedef __attribute__((ext_vector_type(8))) short  short8;
typedef __attribute__((ext_vector_type(4))) float  floatx4;

__device__ __forceinline__ u16 f2bf(float x) {          // round-to-nearest-even
  u32 u = __float_as_uint(x);
  return (u16)((u + 0x7fff + ((u >> 16) & 1)) >> 16);
}
__device__ __forceinline__ float bf2f(u16 b) {
  return __uint_as_float(((u32)b) << 16);
}

// ---------------- CSR build (group edges by dst) ----------------
__global__ void k_count(const int* __restrict__ dst, int* __restrict__ cnt) {
  int e = blockIdx.x * 256 + threadIdx.x;
  if (e < NE) atomicAdd(&cnt[dst[e]], 1);
}

__global__ __launch_bounds__(1024) void k_scan(const int* __restrict__ cnt,
    int* __restrict__ rowptr, int* __restrict__ cursor) {
  __shared__ int sh[1024];
  int tid = threadIdx.x;
  const int CH = 20;                      // 1024*20 >= NN
  int base = tid * CH;
  int local[CH];
  int s = 0;
  #pragma unroll
  for (int i = 0; i < CH; i++) {
    int idx = base + i;
    int v = (idx < NN) ? cnt[idx] : 0;
    local[i] = s;
    s += v;
  }
  sh[tid] = s;
  __syncthreads();
  for (int off = 1; off < 1024; off <<= 1) {
    int tv = (tid >= off) ? sh[tid - off] : 0;
    __syncthreads();
    sh[tid] += tv;
    __syncthreads();
  }
  int pre = (tid > 0) ? sh[tid - 1] : 0;
  #pragma unroll
  for (int i = 0; i < CH; i++) {
    int idx = base + i;
    if (idx < NN) { int e = pre + local[i]; rowptr[idx] = e; cursor[idx] = e; }
  }
  if (tid == 1023) rowptr[NN] = sh[1023];
}

__global__ void k_fill(const int* __restrict__ src, const int* __restrict__ dst,
    int* __restrict__ cursor, int* __restrict__ col, int* __restrict__ row) {
  int e = blockIdx.x * 256 + threadIdx.x;
  if (e < NE) {
    int d = dst[e];
    int pos = atomicAdd(&cursor[d], 1);
    col[pos] = src[e];
    row[pos] = d;
  }
}

// ---------------- weight prep ----------------
// LSTM weights, GATE-INTERLEAVED: Bt[4c+g][k] = W[g*128+c][k], W = [Wih | Whh]
__global__ void k_prepw_lstm(const float* __restrict__ Wih, const float* __restrict__ Whh,
    u16* __restrict__ Bt) {
  int idx = blockIdx.x * 256 + threadIdx.x;
  if (idx < 512 * 256) {
    int jp = idx >> 8, k = idx & 255;
    int c = jp >> 2, g = jp & 3;
    int j = g * 128 + c;
    float v = (k < 128) ? Wih[(size_t)j * 128 + k] : Whh[(size_t)j * 128 + (k - 128)];
    Bt[idx] = f2bf(v);
  }
}
// combined bias, gate-interleaved: bs[4c+g] = bih[g*128+c] + bhh[g*128+c]; 2 cells
__global__ void k_prepb(const float* __restrict__ bih0, const float* __restrict__ bhh0,
    const float* __restrict__ bih1, const float* __restrict__ bhh1,
    float* __restrict__ bs01) {
  int t = threadIdx.x;               // 512 per block, blockIdx.x = cell
  const float* bih = blockIdx.x ? bih1 : bih0;
  const float* bhh = blockIdx.x ? bhh1 : bhh0;
  int c = t >> 2, g = t & 3;
  bs01[blockIdx.x * 512 + t] = bih[g * 128 + c] + bhh[g * 128 + c];
}
// GAT: Btg[l][n][k] = gatW[l][k][n]
__global__ void k_prepw_gat(const float* __restrict__ gatW, u16* __restrict__ Btg) {
  int idx = blockIdx.x * 256 + threadIdx.x;
  if (idx < NL * 128 * 128) {
    int l = idx >> 14, r = idx & 16383;
    int n = r >> 7, k = r & 127;
    Btg[idx] = f2bf(gatW[(size_t)l * 16384 + k * 128 + n]);
  }
}

// ---------------- input projection (TC timesteps) ----------------
__global__ __launch_bounds__(256) void k_proj(const float* __restrict__ xs,
    const float* __restrict__ xdt, const float* __restrict__ W,
    const float* __restrict__ b, u16* __restrict__ hbf) {
  __shared__ float Ws[24 * HID];
  __shared__ float xin[16][24];
  int tid = threadIdx.x;
  int tc = blockIdx.y;
  for (int i = tid; i < 24 * HID; i += 256) Ws[i] = W[i];
  int n0 = blockIdx.x * 16;
  for (int i = tid; i < 16 * 24; i += 256) {
    int r = i / 24, c = i % 24;
    int n = n0 + r;
    xin[r][c] = (c < SDIM) ? xs[(size_t)n * SDIM + c]
                           : xdt[(size_t)tc * NN * DDIM + (size_t)n * DDIM + (c - SDIM)];
  }
  __syncthreads();
  int ch = tid & 127, rb = (tid >> 7) * 8;
  for (int r = rb; r < rb + 8; r++) {
    float acc = b[ch];
    #pragma unroll
    for (int k = 0; k < 24; k++) acc = fmaf(xin[r][k], Ws[k * HID + ch], acc);
    hbf[((size_t)tc * NN + n0 + r) * HID + ch] = f2bf(acc);
  }
}

#define TBM 128
#define TBN 64
#define TBK 64

// ---------------- GAT GEMM + fused attention-logit epilogue ----------------
__global__ __launch_bounds__(256) void k_bgemm_gat(const u16* __restrict__ A,
    const u16* __restrict__ Bt, const float* __restrict__ as_,
    const float* __restrict__ ad_, u16* __restrict__ xpbf,
    float* __restrict__ asrc, float* __restrict__ adst, int M) {
  __shared__ u16 As[TBM][TBK + 8];
  __shared__ u16 Bs[TBN][TBK + 8];
  int tid = threadIdx.x;
  int wid = tid >> 6, lane = tid & 63;
  int wr = wid >> 1, wc = wid & 1;
  int lrow = lane & 15, lgrp = lane >> 4;
  int row0 = blockIdx.x * TBM, col0 = blockIdx.y * TBN;
  floatx4 acc[4][2] = {};
  for (int k0 = 0; k0 < 128; k0 += TBK) {
    #pragma unroll
    for (int i = 0; i < 4; i++) {
      int idx = tid + i * 256;
      int r = idx >> 3, g = idx & 7;
      int gr = row0 + r;
      short8 v = {};
      if (gr < M) v = *(const short8*)(A + (size_t)gr * 128 + k0 + g * 8);
      *(short8*)&As[r][g * 8] = v;
    }
    #pragma unroll
    for (int i = 0; i < 2; i++) {
      int idx = tid + i * 256;
      int r = idx >> 3, g = idx & 7;
      *(short8*)&Bs[r][g * 8] = *(const short8*)(Bt + (size_t)(col0 + r) * 128 + k0 + g * 8);
    }
    __syncthreads();
    #pragma unroll
    for (int kk = 0; kk < TBK; kk += 32) {
      short8 bfr[2];
      #pragma unroll
      for (int n = 0; n < 2; n++)
        bfr[n] = *(const short8*)&Bs[wc * 32 + n * 16 + lrow][kk + lgrp * 8];
      #pragma unroll
      for (int m = 0; m < 4; m++) {
        short8 af = *(const short8*)&As[wr * 64 + m * 16 + lrow][kk + lgrp * 8];
        acc[m][0] = __builtin_amdgcn_mfma_f32_16x16x32_bf16(af, bfr[0], acc[m][0], 0, 0, 0);
        acc[m][1] = __builtin_amdgcn_mfma_f32_16x16x32_bf16(af, bfr[1], acc[m][1], 0, 0, 0);
      }
    }
    __syncthreads();
  }
  int head = (col0 >> 5) + wc;
  float as0 = as_[head * 32 + lrow], as1 = as_[head * 32 + 16 + lrow];
  float ad0 = ad_[head * 32 + lrow], ad1 = ad_[head * 32 + 16 + lrow];
  #pragma unroll
  for (int m = 0; m < 4; m++) {
    #pragma unroll
    for (int r = 0; r < 4; r++) {
      int grow = row0 + wr * 64 + m * 16 + lgrp * 4 + r;
      float v0 = acc[m][0][r], v1 = acc[m][1][r];
      if (grow < M) {
        xpbf[(size_t)grow * HID + col0 + wc * 32 + lrow]      = f2bf(v0);
        xpbf[(size_t)grow * HID + col0 + wc * 32 + 16 + lrow] = f2bf(v1);
      }
      float ps = v0 * as0 + v1 * as1;
      float pd = v0 * ad0 + v1 * ad1;
      #pragma unroll
      for (int off = 1; off < 16; off <<= 1) {
        ps += __shfl_xor(ps, off);
        pd += __shfl_xor(pd, off);
      }
      if (lrow == 0 && grow < M) {
        asrc[grow * HEADS + head] = ps;
        adst[grow * HEADS + head] = pd;
      }
    }
  }
}

// ---------------- edge-weight precompute: ewp[tc][j] = bf16x4 (4 heads) packed u64 ----
__global__ __launch_bounds__(256) void k_edgew(const int* __restrict__ col,
    const int* __restrict__ row, const float* __restrict__ asrc,
    const float* __restrict__ adst, u64* __restrict__ ewp) {
  int idx = blockIdx.x * 256 + threadIdx.x;       // TC*NE exactly
  int tc = idx / NE;
  int j = idx - tc * NE;
  int base = tc * NN;
  float4 a = *(const float4*)(asrc + (size_t)(base + col[j]) * HEADS);
  float4 b = *(const float4*)(adst + (size_t)(base + row[j]) * HEADS);
  float e0 = a.x + b.x, e1 = a.y + b.y, e2 = a.z + b.z, e3 = a.w + b.w;
  e0 = (e0 > 0.f) ? e0 : 0.2f * e0;
  e1 = (e1 > 0.f) ? e1 : 0.2f * e1;
  e2 = (e2 > 0.f) ? e2 : 0.2f * e2;
  e3 = (e3 > 0.f) ? e3 : 0.2f * e3;
  u64 w = (u64)f2bf(__expf(fminf(e0, 80.f)))
        | ((u64)f2bf(__expf(fminf(e1, 80.f))) << 16)
        | ((u64)f2bf(__expf(fminf(e2, 80.f))) << 32)
        | ((u64)f2bf(__expf(fminf(e3, 80.f))) << 48);
  ewp[idx] = w;
}

// ---------------- GAT aggregation + residual + LayerNorm + ReLU (TC-batched) ----------------
// cooperative preload: wave loads col/ewp for a 64-edge tile coalesced ONCE, then the
// edge loop uses register broadcasts (shfl) — gather is the only memory op in the loop.
__global__ __launch_bounds__(256) void k_aggr(const u16* __restrict__ xpbf,
    u16* __restrict__ hbf, const float* __restrict__ asrc,
    const float* __restrict__ adst, const u64* __restrict__ ewp,
    const int* __restrict__ rowptr, const int* __restrict__ col,
    const float* __restrict__ bias, const float* __restrict__ lng,
    const float* __restrict__ lnb) {
  int wid = threadIdx.x >> 6, lane = threadIdx.x & 63;
  int n = blockIdx.x * 4 + wid;                    // 0 .. TC*NN
  int tc = n / NN;
  int node = n - tc * NN, base = tc * NN;
  int hh = lane >> 4;
  bool uselo = hh < 2;                             // which u32 half of packed w
  int hs2 = (hh & 1) * 16;                         // shift within the half
  float ad = adst[n * HEADS + hh];
  float e0 = asrc[n * HEADS + hh] + ad;            // self-loop (fp32 weight)
  e0 = (e0 > 0.f) ? e0 : 0.2f * e0;
  float w0 = __expf(fminf(e0, 80.f));
  u32 xv = ((const u32*)(xpbf + (size_t)n * HID))[lane];
  int c0 = lane * 2;
  size_t hoff = (size_t)n * HID + c0;
  u32 hv = *(const u32*)(hbf + hoff);              // residual (load early, store later)
  float den0 = w0, den1 = 0.f, den2 = 0.f, den3 = 0.f;
  float p00 = w0 * bf2f((u16)(xv & 0xffff)), p10 = 0.f, p20 = 0.f, p30 = 0.f;
  float p01 = w0 * bf2f((u16)(xv >> 16)),    p11 = 0.f, p21 = 0.f, p31 = 0.f;
  const u64* ewrow = ewp + (size_t)tc * NE;
  int rs = rowptr[node], re = rowptr[node + 1];
  for (int tile = rs; tile < re; tile += 64) {
    int cnt = re - tile; if (cnt > 64) cnt = 64;
    int cl = 0; u32 wlo = 0, whi = 0;
    if (tile + lane < re) {
      cl = col[tile + lane];                       // coalesced, once per tile
      u64 wl = ewrow[tile + lane];                 // coalesced, once per tile
      wlo = (u32)wl; whi = (u32)(wl >> 32);
    }
    int k = 0;
    for (; k + 4 <= cnt; k += 4) {                 // broadcasts + pure gathers
      int s0 = base + __shfl(cl, k + 0);
      int s1 = base + __shfl(cl, k + 1);
      int s2 = base + __shfl(cl, k + 2);
      int s3 = base + __shfl(cl, k + 3);
      u32 l0 = __shfl((int)wlo, k + 0), h0 = __shfl((int)whi, k + 0);
      u32 l1 = __shfl((int)wlo, k + 1), h1 = __shfl((int)whi, k + 1);
      u32 l2 = __shfl((int)wlo, k + 2), h2 = __shfl((int)whi, k + 2);
      u32 l3 = __shfl((int)wlo, k + 3), h3 = __shfl((int)whi, k + 3);
      u32 x0 = ((const u32*)(xpbf + (size_t)s0 * HID))[lane];
      u32 x1 = ((const u32*)(xpbf + (size_t)s1 * HID))[lane];
      u32 x2 = ((const u32*)(xpbf + (size_t)s2 * HID))[lane];
      u32 x3 = ((const u32*)(xpbf + (size_t)s3 * HID))[lane];
      float w0e = bf2f((u16)(((uselo ? l0 : h0) >> hs2) & 0xffff));
      float w1e = bf2f((u16)(((uselo ? l1 : h1) >> hs2) & 0xffff));
      float w2e = bf2f((u16)(((uselo ? l2 : h2) >> hs2) & 0xffff));
      float w3e = bf2f((u16)(((uselo ? l3 : h3) >> hs2) & 0xffff));
      den0 += w0e; den1 += w1e; den2 += w2e; den3 += w3e;
      p00 = fmaf(w0e, bf2f((u16)(x0 & 0xffff)), p00);
      p10 = fmaf(w1e, bf2f((u16)(x1 & 0xffff)), p10);
      p20 = fmaf(w2e, bf2f((u16)(x2 & 0xffff)), p20);
      p30 = fmaf(w3e, bf2f((u16)(x3 & 0xffff)), p30);
      p01 = fmaf(w0e, bf2f((u16)(x0 >> 16)), p01);
      p11 = fmaf(w1e, bf2f((u16)(x1 >> 16)), p11);
      p21 = fmaf(w2e, bf2f((u16)(x2 >> 16)), p21);
      p31 = fmaf(w3e, bf2f((u16)(x3 >> 16)), p31);
    }
    for (; k < cnt; k++) {
      int s0 = base + __shfl(cl, k);
      u32 lw = __shfl((int)wlo, k), hw = __shfl((int)whi, k);
      u32 x0 = ((const u32*)(xpbf + (size_t)s0 * HID))[lane];
      float w = bf2f((u16)(((uselo ? lw : hw) >> hs2) & 0xffff));
      den0 += w;
      p00 = fmaf(w, bf2f((u16)(x0 & 0xffff)), p00);
      p01 = fmaf(w, bf2f((u16)(x0 >> 16)), p01);
    }
  }
  float den = (den0 + den1) + (den2 + den3);
  float mg0 = (p00 + p10) + (p20 + p30);
  float mg1 = (p01 + p11) + (p21 + p31);
  float inv = 1.f / (den + 1e-16f);
  float o0 = mg0 * inv + bias[c0]     + bf2f((u16)(hv & 0xffff));
  float o1 = mg1 * inv + bias[c0 + 1] + bf2f((u16)(hv >> 16));
  float s2 = o0 + o1;
  #pragma unroll
  for (int off = 32; off; off >>= 1) s2 += __shfl_xor(s2, off);
  float mu = s2 * (1.f / HID);
  float d0 = o0 - mu, d1 = o1 - mu;
  float v2 = d0 * d0 + d1 * d1;
  #pragma unroll
  for (int off = 32; off; off >>= 1) v2 += __shfl_xor(v2, off);
  float rstd = rsqrtf(v2 * (1.f / HID) + 1e-5f);
  o0 = lng[c0] * d0 * rstd + lnb[c0];
  o1 = lng[c0 + 1] * d1 * rstd + lnb[c0 + 1];
  o0 = fmaxf(o0, 0.f);
  o1 = fmaxf(o1, 0.f);
  *(u32*)(hbf + hoff) = (u32)f2bf(o0) | ((u32)f2bf(o1) << 16);
}

// ---------------- LSTM GEMM + fused gate epilogue (shared body) ----------------
__device__ __forceinline__ void lstm_body(const u16* __restrict__ A0,
    const u16* __restrict__ A1, const u16* __restrict__ Bt,
    const float* __restrict__ bs, float* __restrict__ cst,
    u16* __restrict__ hout, char* smem, int bx, int by) {
  u16 (*As)[TBK + 8] = (u16(*)[TBK + 8])smem;
  u16 (*Bs)[TBK + 8] = (u16(*)[TBK + 8])(smem + TBM * (TBK + 8) * 2);
  float (*zs)[68] = (float(*)[68])smem;
  int tid = threadIdx.x;
  int wid = tid >> 6, lane = tid & 63;
  int wr = wid >> 1, wc = wid & 1;
  int lrow = lane & 15, lgrp = lane >> 4;
  int row0 = bx * TBM, col0 = by * TBN;
  floatx4 acc[4][2] = {};
  for (int k0 = 0; k0 < 256; k0 += TBK) {
    const u16* Ap = (k0 < 128) ? A0 : A1;
    int kb = k0 & 127;
    #pragma unroll
    for (int i = 0; i < 4; i++) {
      int idx = tid + i * 256;
      int r = idx >> 3, g = idx & 7;
      int gr = row0 + r;
      short8 v = {};
      if (gr < NN) v = *(const short8*)(Ap + (size_t)gr * 128 + kb + g * 8);
      *(short8*)&As[r][g * 8] = v;
    }
    #pragma unroll
    for (int i = 0; i < 2; i++) {
      int idx = tid + i * 256;
      int r = idx >> 3, g = idx & 7;
      *(short8*)&Bs[r][g * 8] = *(const short8*)(Bt + (size_t)(col0 + r) * 256 + k0 + g * 8);
    }
    __syncthreads();
    #pragma unroll
    for (int kk = 0; kk < TBK; kk += 32) {
      short8 bfr[2];
      #pragma unroll
      for (int n = 0; n < 2; n++)
        bfr[n] = *(const short8*)&Bs[wc * 32 + n * 16 + lrow][kk + lgrp * 8];
      #pragma unroll
      for (int m = 0; m < 4; m++) {
        short8 af = *(const short8*)&As[wr * 64 + m * 16 + lrow][kk + lgrp * 8];
        acc[m][0] = __builtin_amdgcn_mfma_f32_16x16x32_bf16(af, bfr[0], acc[m][0], 0, 0, 0);
        acc[m][1] = __builtin_amdgcn_mfma_f32_16x16x32_bf16(af, bfr[1], acc[m][1], 0, 0, 0);
      }
    }
    __syncthreads();
  }
  #pragma unroll
  for (int m = 0; m < 4; m++)
    #pragma unroll
    for (int n = 0; n < 2; n++)
      #pragma unroll
      for (int r = 0; r < 4; r++)
        zs[wr * 64 + m * 16 + lgrp * 4 + r][wc * 32 + n * 16 + lrow] = acc[m][n][r];
  __syncthreads();
  int ch0 = by * 16;
  #pragma unroll
  for (int it = 0; it < 8; it++) {
    int o = tid + it * 256;
    int r = o >> 4, lc = o & 15;
    int grow = row0 + r;
    if (grow < NN) {
      float4 zi = *(float4*)&zs[r][lc * 4];
      int ch = ch0 + lc;
      size_t gi = (size_t)grow * HID + ch;
      float ii = zi.x + bs[4 * ch + 0];
      float ff = zi.y + bs[4 * ch + 1];
      float gg = zi.z + bs[4 * ch + 2];
      float oo = zi.w + bs[4 * ch + 3];
      float si = 1.f / (1.f + __expf(-ii));
      float sf = 1.f / (1.f + __expf(-ff));
      float so = 1.f / (1.f + __expf(-oo));
      float tg = tanhf(gg);
      float cn = sf * cst[gi] + si * tg;
      cst[gi] = cn;
      hout[gi] = f2bf(so * tanhf(cn));
    }
  }
}

__global__ __launch_bounds__(256) void k_lstm1(const u16* __restrict__ A0,
    const u16* __restrict__ A1, const u16* __restrict__ Bt,
    const float* __restrict__ bs, float* __restrict__ cst, u16* __restrict__ hout) {
  __shared__ __align__(16) char smem[34816];
  lstm_body(A0, A1, Bt, bs, cst, hout, smem, blockIdx.x, blockIdx.y);
}

// merged: z==0 -> cell1(t), z==1 -> cell0(t+1) — independent jobs
__global__ __launch_bounds__(256) void k_lstm2(
    const u16* __restrict__ A0a, const u16* __restrict__ A1a, const u16* __restrict__ Bta,
    const float* __restrict__ bsa, float* __restrict__ csta, u16* __restrict__ houta,
    const u16* __restrict__ A0b, const u16* __restrict__ A1b, const u16* __restrict__ Btb,
    const float* __restrict__ bsb, float* __restrict__ cstb, u16* __restrict__ houtb) {
  __shared__ __align__(16) char smem[34816];
  if (blockIdx.z == 0) lstm_body(A0a, A1a, Bta, bsa, csta, houta, smem, blockIdx.x, blockIdx.y);
  else                 lstm_body(A0b, A1b, Btb, bsb, cstb, houtb, smem, blockIdx.x, blockIdx.y);
}

// ---------------- output MLP: relu(h1@W1+b1)@W2+b2 ----------------
__global__ __launch_bounds__(64) void k_mlp(const u16* __restrict__ h1,
    const float* __restrict__ W1, const float* __restrict__ b1,
    const float* __restrict__ W2, const float* __restrict__ b2,
    float* __restrict__ out) {
  int n = blockIdx.x, j = threadIdx.x;
  const u16* hr = h1 + (size_t)n * HID;
  float acc = b1[j];
  #pragma unroll 8
  for (int k = 0; k < HID; k++) acc = fmaf(bf2f(hr[k]), W1[(size_t)k * 64 + j], acc);
  acc = fmaxf(acc, 0.f);
  float p = acc * W2[j];
  #pragma unroll
  for (int off = 32; off; off >>= 1) p += __shfl_xor(p, off);
  if (j == 0) out[n] = p + b2[0];
}

extern "C" void kernel_launch(void* const* d_in, const int* in_sizes, int n_in,
                              void* d_out, int out_size, void* d_ws, size_t ws_size,
                              hipStream_t stream) {
  const float* xs    = (const float*)d_in[0];
  const float* xd    = (const float*)d_in[1];
  const int*   ei    = (const int*)d_in[2];
  const float* projW = (const float*)d_in[3];
  const float* projb = (const float*)d_in[4];
  const float* gatW  = (const float*)d_in[5];
  const float* attS  = (const float*)d_in[6];
  const float* attD  = (const float*)d_in[7];
  const float* gatb  = (const float*)d_in[8];
  const float* lng   = (const float*)d_in[9];
  const float* lnb   = (const float*)d_in[10];
  const float* Wih0  = (const float*)d_in[11];
  const float* Whh0  = (const float*)d_in[12];
  const float* bih0  = (const float*)d_in[13];
  const float* bhh0  = (const float*)d_in[14];
  const float* Wih1  = (const float*)d_in[15];
  const float* Whh1  = (const float*)d_in[16];
  const float* bih1  = (const float*)d_in[17];
  const float* bhh1  = (const float*)d_in[18];
  const float* oW1   = (const float*)d_in[19];
  const float* ob1   = (const float*)d_in[20];
  const float* oW2   = (const float*)d_in[21];
  const float* ob2   = (const float*)d_in[22];
  float* out = (float*)d_out;

  // -------- workspace layout (~87 MB) --------
  char* w = (char*)d_ws;
  size_t off = 0;
  auto alloc = [&](size_t bytes) { void* p = w + off; off += (bytes + 255) & ~(size_t)255; return p; };
  u16*   hbf   = (u16*)  alloc((size_t)TC * NN * HID * 2);   // bf16 h (GEMM A + residual)
  u16*   xpbf  = (u16*)  alloc((size_t)TC * NN * HID * 2);   // bf16 xp
  float* asrc  = (float*)alloc((size_t)TC * NN * HEADS * 4);
  float* adst  = (float*)alloc((size_t)TC * NN * HEADS * 4);
  u64*   ewp   = (u64*)  alloc((size_t)TC * NE * 8);         // 10.2 MB packed bf16x4 weights
  float* c01   = (float*)alloc((size_t)2 * NN * HID * 4);    // c0,c1
  float* c0 = c01, *c1 = c01 + (size_t)NN * HID;
  u16*   h0p   = (u16*)  alloc((size_t)2 * NN * HID * 2);    // h0 ping-pong
  u16*   h1p   = (u16*)  alloc((size_t)2 * NN * HID * 2);    // h1 ping-pong
  u16*   h0buf[2] = { h0p, h0p + (size_t)NN * HID };
  u16*   h1buf[2] = { h1p, h1p + (size_t)NN * HID };
  u16*   Wc0bf = (u16*)alloc((size_t)512 * 256 * 2);
  u16*   Wc1bf = (u16*)alloc((size_t)512 * 256 * 2);
  float* bs01  = (float*)alloc((size_t)1024 * 4);
  float* bs0 = bs01, *bs1 = bs01 + 512;
  u16*   gatWbf= (u16*)alloc((size_t)NL * 128 * 128 * 2);
  int* cnt    = (int*)alloc((size_t)NN * 4);
  int* rowptr = (int*)alloc((size_t)(NN + 1) * 4);
  int* cursor = (int*)alloc((size_t)NN * 4);
  int* col    = (int*)alloc((size_t)NE * 4);
  int* rowi   = (int*)alloc((size_t)NE * 4);

  const int* esrc = ei;
  const int* edst = ei + NE;

  // -------- CSR (edge_index identical across t and layers) --------
  hipMemsetAsync(cnt, 0, (size_t)NN * 4, stream);
  k_count<<<(NE + 255) / 256, 256, 0, stream>>>(edst, cnt);
  k_scan<<<1, 1024, 0, stream>>>(cnt, rowptr, cursor);
  k_fill<<<(NE + 255) / 256, 256, 0, stream>>>(esrc, edst, cursor, col, rowi);

  // -------- weight/bias prep + state init --------
  k_prepw_lstm<<<(512 * 256) / 256, 256, 0, stream>>>(Wih0, Whh0, Wc0bf);
  k_prepw_lstm<<<(512 * 256) / 256, 256, 0, stream>>>(Wih1, Whh1, Wc1bf);
  k_prepb<<<2, 512, 0, stream>>>(bih0, bhh0, bih1, bhh1, bs01);
  k_prepw_gat<<<(NL * 128 * 128) / 256, 256, 0, stream>>>(gatW, gatWbf);
  hipMemsetAsync(c01, 0, (size_t)2 * NN * HID * 4, stream);
  hipMemsetAsync(h0buf[0], 0, (size_t)NN * HID * 2, stream);
  hipMemsetAsync(h1buf[0], 0, (size_t)NN * HID * 2, stream);

  const int gx  = (NN + TBM - 1) / TBM;             // 157
  const int gx2 = (TC * NN + TBM - 1) / TBM;        // 625

  auto gnn_chunk = [&](int tcb) {
    k_proj<<<dim3(NN / 16, TC), 256, 0, stream>>>(
        xs, xd + (size_t)(tcb * TC) * NN * DDIM, projW, projb, hbf);
    for (int l = 0; l < NL; l++) {
      k_bgemm_gat<<<dim3(gx2, 2), 256, 0, stream>>>(
          hbf, gatWbf + (size_t)l * 128 * 128,
          attS + l * HEADS * DPH, attD + l * HEADS * DPH,
          xpbf, asrc, adst, TC * NN);
      k_edgew<<<(TC * NE) / 256, 256, 0, stream>>>(col, rowi, asrc, adst, ewp);
      k_aggr<<<TC * NN / 4, 256, 0, stream>>>(
          xpbf, hbf, asrc, adst, ewp, rowptr, col, gatb + (size_t)l * HID,
          lng + (size_t)l * HID, lnb + (size_t)l * HID);
    }
  };
  // merged LSTM step: cell1(t) + cell0(t+1)  [independent; buffer audit in journal]
  auto lstm_merged = [&](int t) {
    int pi = t & 1;
    int s1 = (t + 1) & (TC - 1);                   // hbf slot of t+1 within its chunk
    k_lstm2<<<dim3(gx, 8, 2), 256, 0, stream>>>(
        h0buf[pi ^ 1], h1buf[pi], Wc1bf, bs1, c1, h1buf[pi ^ 1],
        hbf + (size_t)s1 * NN * HID, h0buf[pi ^ 1], Wc0bf, bs0, c0, h0buf[pi]);
  };

  // -------- pipeline: GNN chunks + dependency-merged LSTM chain --------
  gnn_chunk(0);
  k_lstm1<<<dim3(gx, 8), 256, 0, stream>>>(hbf, h0buf[0], Wc0bf, bs0, c0, h0buf[1]);  // cell0(t=0)
  lstm_merged(0); lstm_merged(1); lstm_merged(2);
  for (int tcb = 1; tcb < TT / TC; tcb++) {
    gnn_chunk(tcb);
    lstm_merged(4 * tcb - 1);
    lstm_merged(4 * tcb);
    lstm_merged(4 * tcb + 1);
    if (tcb < TT / TC - 1) lstm_merged(4 * tcb + 2);
    else {
      lstm_merged(4 * tcb + 2);                    // t=22
      // final cell1(t=23): reads h0buf[0], h1buf[1] -> h1buf[0]
      k_lstm1<<<dim3(gx, 8), 256, 0, stream>>>(h0buf[0], h1buf[1], Wc1bf, bs1, c1, h1buf[0]);
    }
  }

  // TT even -> final h1 lives in h1buf[0]
  k_mlp<<<NN, 64, 0, stream>>>(h1buf[0], oW1, ob1, oW2, ob2, out);
}